// Round 1
// baseline (1096.670 us; speedup 1.0000x reference)
//
#include <hip/hip_runtime.h>
#include <math.h>

#define N_FIN 128
#define C1    256   // HEADS*HID
#define NH    4
#define HD    64
#define G3    192   // 3*HID

static __device__ __forceinline__ float lrelu(float x) { return x >= 0.0f ? x : 0.2f * x; }
static __device__ __forceinline__ float sigm(float x)  { return 1.0f / (1.0f + __expf(-x)); }

// ---------------------------------------------------------------- CSR build
__global__ __launch_bounds__(256) void k_deg_init(int n, int* __restrict__ deg)
{
    int i = blockIdx.x * blockDim.x + threadIdx.x;
    if (i < n) deg[i] = 1;  // self-loop
}

__global__ __launch_bounds__(256) void k_hist(int E, const int* __restrict__ edst, int* __restrict__ deg)
{
    int e = blockIdx.x * blockDim.x + threadIdx.x;
    if (e < E) atomicAdd(&deg[edst[e]], 1);
}

__global__ __launch_bounds__(1024) void k_scan_block(int n, const int* __restrict__ deg,
                                                     int* __restrict__ incl, int* __restrict__ bsum)
{
    __shared__ int sh[1024];
    int t = threadIdx.x;
    int i = blockIdx.x * 1024 + t;
    sh[t] = (i < n) ? deg[i] : 0;
    __syncthreads();
    #pragma unroll
    for (int off = 1; off < 1024; off <<= 1) {
        int u = (t >= off) ? sh[t - off] : 0;
        __syncthreads();
        sh[t] += u;
        __syncthreads();
    }
    if (i < n) incl[i] = sh[t];
    if (t == 1023) bsum[blockIdx.x] = sh[1023];
}

__global__ void k_scan_bsum(int nb, int* __restrict__ bsum)
{
    if (threadIdx.x == 0 && blockIdx.x == 0) {
        int run = 0;
        for (int b = 0; b < nb; ++b) { int v = bsum[b]; bsum[b] = run; run += v; }
    }
}

__global__ __launch_bounds__(256) void k_rowptr(int n, const int* __restrict__ incl,
                                                const int* __restrict__ bsum, int* __restrict__ rowptr)
{
    int i = blockIdx.x * blockDim.x + threadIdx.x;
    if (i < n) rowptr[i + 1] = incl[i] + bsum[i >> 10];
    if (i == 0) rowptr[0] = 0;
}

__global__ __launch_bounds__(256) void k_cursor(int n, const int* __restrict__ rowptr, int* __restrict__ cursor)
{
    int i = blockIdx.x * blockDim.x + threadIdx.x;
    if (i < n) cursor[i] = rowptr[i];
}

__global__ __launch_bounds__(256) void k_fill(int E, int n, const int* __restrict__ esrc,
                                              const int* __restrict__ edst,
                                              int* __restrict__ cursor, int* __restrict__ col)
{
    int t = blockIdx.x * blockDim.x + threadIdx.x;
    if (t < E) {
        int p = atomicAdd(&cursor[edst[t]], 1);
        col[p] = esrc[t];
    } else if (t < E + n) {
        int v = t - E;
        int p = atomicAdd(&cursor[v], 1);
        col[p] = v;   // self-loop
    }
}

// ---------------------------------------------------------------- fp32 GEMM (NN): C[M,N] = A[M,K] @ B[K,N]
__global__ __launch_bounds__(256) void sgemm_nn(int M, int N, int K,
    const float* __restrict__ A, int lda, const float* __restrict__ B, int ldb,
    float* __restrict__ C, int ldc)
{
    __shared__ float As[16][65];
    __shared__ float Bs[16][64];
    const int tid = threadIdx.x;
    const int tx = tid & 15, ty = tid >> 4;
    const int row0 = blockIdx.x * 64, col0 = blockIdx.y * 64;
    const int ar = tid >> 2, akq = (tid & 3) << 2;
    const int bk = tid >> 4, bc = (tid & 15) << 2;
    float acc[4][4] = {};
    for (int k0 = 0; k0 < K; k0 += 16) {
        int arow = row0 + ar; arow = arow < M ? arow : M - 1;
        float4 av = *reinterpret_cast<const float4*>(A + (size_t)arow * lda + k0 + akq);
        float4 bv = *reinterpret_cast<const float4*>(B + (size_t)(k0 + bk) * ldb + col0 + bc);
        As[akq + 0][ar] = av.x; As[akq + 1][ar] = av.y; As[akq + 2][ar] = av.z; As[akq + 3][ar] = av.w;
        *reinterpret_cast<float4*>(&Bs[bk][bc]) = bv;
        __syncthreads();
        #pragma unroll
        for (int k = 0; k < 16; ++k) {
            float a0 = As[k][ty * 4 + 0], a1 = As[k][ty * 4 + 1];
            float a2 = As[k][ty * 4 + 2], a3 = As[k][ty * 4 + 3];
            float4 b4 = *reinterpret_cast<const float4*>(&Bs[k][tx * 4]);
            acc[0][0] += a0 * b4.x; acc[0][1] += a0 * b4.y; acc[0][2] += a0 * b4.z; acc[0][3] += a0 * b4.w;
            acc[1][0] += a1 * b4.x; acc[1][1] += a1 * b4.y; acc[1][2] += a1 * b4.z; acc[1][3] += a1 * b4.w;
            acc[2][0] += a2 * b4.x; acc[2][1] += a2 * b4.y; acc[2][2] += a2 * b4.z; acc[2][3] += a2 * b4.w;
            acc[3][0] += a3 * b4.x; acc[3][1] += a3 * b4.y; acc[3][2] += a3 * b4.z; acc[3][3] += a3 * b4.w;
        }
        __syncthreads();
    }
    #pragma unroll
    for (int i = 0; i < 4; ++i) {
        int r = row0 + ty * 4 + i;
        if (r < M) {
            float4 o = make_float4(acc[i][0], acc[i][1], acc[i][2], acc[i][3]);
            *reinterpret_cast<float4*>(C + (size_t)r * ldc + col0 + tx * 4) = o;
        }
    }
}

// ---------------------------------------------------------------- fp32 GEMM (NT): C[M,N] = A[M,K] @ B[N,K]^T
__global__ __launch_bounds__(256) void sgemm_nt(int M, int N, int K,
    const float* __restrict__ A, int lda, const float* __restrict__ B, int ldb,
    float* __restrict__ C, int ldc)
{
    __shared__ float As[16][65];
    __shared__ float Bs[16][65];
    const int tid = threadIdx.x;
    const int tx = tid & 15, ty = tid >> 4;
    const int row0 = blockIdx.x * 64, col0 = blockIdx.y * 64;
    const int ar = tid >> 2, akq = (tid & 3) << 2;  // also used for B (row-of-B = output col)
    float acc[4][4] = {};
    for (int k0 = 0; k0 < K; k0 += 16) {
        int arow = row0 + ar; arow = arow < M ? arow : M - 1;
        float4 av = *reinterpret_cast<const float4*>(A + (size_t)arow * lda + k0 + akq);
        float4 bv = *reinterpret_cast<const float4*>(B + (size_t)(col0 + ar) * ldb + k0 + akq);
        As[akq + 0][ar] = av.x; As[akq + 1][ar] = av.y; As[akq + 2][ar] = av.z; As[akq + 3][ar] = av.w;
        Bs[akq + 0][ar] = bv.x; Bs[akq + 1][ar] = bv.y; Bs[akq + 2][ar] = bv.z; Bs[akq + 3][ar] = bv.w;
        __syncthreads();
        #pragma unroll
        for (int k = 0; k < 16; ++k) {
            float a0 = As[k][ty * 4 + 0], a1 = As[k][ty * 4 + 1];
            float a2 = As[k][ty * 4 + 2], a3 = As[k][ty * 4 + 3];
            float b0 = Bs[k][tx * 4 + 0], b1 = Bs[k][tx * 4 + 1];
            float b2 = Bs[k][tx * 4 + 2], b3 = Bs[k][tx * 4 + 3];
            acc[0][0] += a0 * b0; acc[0][1] += a0 * b1; acc[0][2] += a0 * b2; acc[0][3] += a0 * b3;
            acc[1][0] += a1 * b0; acc[1][1] += a1 * b1; acc[1][2] += a1 * b2; acc[1][3] += a1 * b3;
            acc[2][0] += a2 * b0; acc[2][1] += a2 * b1; acc[2][2] += a2 * b2; acc[2][3] += a2 * b3;
            acc[3][0] += a3 * b0; acc[3][1] += a3 * b1; acc[3][2] += a3 * b2; acc[3][3] += a3 * b3;
        }
        __syncthreads();
    }
    #pragma unroll
    for (int i = 0; i < 4; ++i) {
        int r = row0 + ty * 4 + i;
        if (r < M) {
            float4 o = make_float4(acc[i][0], acc[i][1], acc[i][2], acc[i][3]);
            *reinterpret_cast<float4*>(C + (size_t)r * ldc + col0 + tx * 4) = o;
        }
    }
}

// ---------------------------------------------------------------- attention coefficients
__global__ __launch_bounds__(256) void k_att1(int n, const float* __restrict__ h1,
    const float* __restrict__ att_src, const float* __restrict__ att_dst,
    float* __restrict__ a_src, float* __restrict__ a_dst)
{
    int v = (blockIdx.x * blockDim.x + threadIdx.x) >> 6;
    int lane = threadIdx.x & 63;
    if (v >= n) return;
    const float* hr = h1 + (size_t)v * C1;
    #pragma unroll
    for (int h = 0; h < NH; ++h) {
        float x = hr[h * HD + lane];
        float ps = x * att_src[h * HD + lane];
        float pd = x * att_dst[h * HD + lane];
        #pragma unroll
        for (int off = 32; off > 0; off >>= 1) {
            ps += __shfl_down(ps, off);
            pd += __shfl_down(pd, off);
        }
        if (lane == 0) { a_src[v * NH + h] = ps; a_dst[v * NH + h] = pd; }
    }
}

__global__ __launch_bounds__(256) void k_att2(int n, const float* __restrict__ h2,
    const float* __restrict__ att_src, const float* __restrict__ att_dst,
    float* __restrict__ a_src, float* __restrict__ a_dst)
{
    int v = (blockIdx.x * blockDim.x + threadIdx.x) >> 6;
    int lane = threadIdx.x & 63;
    if (v >= n) return;
    float x = h2[(size_t)v * HD + lane];
    float ps = x * att_src[lane];
    float pd = x * att_dst[lane];
    #pragma unroll
    for (int off = 32; off > 0; off >>= 1) {
        ps += __shfl_down(ps, off);
        pd += __shfl_down(pd, off);
    }
    if (lane == 0) { a_src[v] = ps; a_dst[v] = pd; }
}

// ---------------------------------------------------------------- GAT aggregation (wave per dst node)
__global__ __launch_bounds__(256) void k_aggr1(int n, const int* __restrict__ rowptr,
    const int* __restrict__ col, const float* __restrict__ h1,
    const float* __restrict__ a_src, const float* __restrict__ a_dst,
    const float* __restrict__ b1, float* __restrict__ x1)
{
    int v = (blockIdx.x * blockDim.x + threadIdx.x) >> 6;
    int lane = threadIdx.x & 63;
    if (v >= n) return;
    int beg = rowptr[v], end = rowptr[v + 1];
    float4 ad = *reinterpret_cast<const float4*>(a_dst + (size_t)v * 4);
    float m0 = -1e30f, m1 = -1e30f, m2 = -1e30f, m3 = -1e30f;
    for (int i = beg; i < end; ++i) {
        int s = col[i];
        float4 as = *reinterpret_cast<const float4*>(a_src + (size_t)s * 4);
        m0 = fmaxf(m0, lrelu(as.x + ad.x)); m1 = fmaxf(m1, lrelu(as.y + ad.y));
        m2 = fmaxf(m2, lrelu(as.z + ad.z)); m3 = fmaxf(m3, lrelu(as.w + ad.w));
    }
    float s0 = 0, s1 = 0, s2 = 0, s3 = 0;
    for (int i = beg; i < end; ++i) {
        int s = col[i];
        float4 as = *reinterpret_cast<const float4*>(a_src + (size_t)s * 4);
        s0 += __expf(lrelu(as.x + ad.x) - m0); s1 += __expf(lrelu(as.y + ad.y) - m1);
        s2 += __expf(lrelu(as.z + ad.z) - m2); s3 += __expf(lrelu(as.w + ad.w) - m3);
    }
    float i0 = 1.0f / (s0 + 1e-16f), i1 = 1.0f / (s1 + 1e-16f);
    float i2 = 1.0f / (s2 + 1e-16f), i3 = 1.0f / (s3 + 1e-16f);
    float acc0 = 0, acc1 = 0, acc2 = 0, acc3 = 0;
    for (int i = beg; i < end; ++i) {
        int s = col[i];
        float4 as = *reinterpret_cast<const float4*>(a_src + (size_t)s * 4);
        float al0 = __expf(lrelu(as.x + ad.x) - m0) * i0;
        float al1 = __expf(lrelu(as.y + ad.y) - m1) * i1;
        float al2 = __expf(lrelu(as.z + ad.z) - m2) * i2;
        float al3 = __expf(lrelu(as.w + ad.w) - m3) * i3;
        const float* hr = h1 + (size_t)s * C1;
        acc0 += hr[lane] * al0;
        acc1 += hr[64 + lane] * al1;
        acc2 += hr[128 + lane] * al2;
        acc3 += hr[192 + lane] * al3;
    }
    size_t o = (size_t)v * C1;
    float r0 = acc0 + b1[lane];        x1[o + lane]       = r0 > 0 ? r0 : 0;
    float r1 = acc1 + b1[64 + lane];   x1[o + 64 + lane]  = r1 > 0 ? r1 : 0;
    float r2 = acc2 + b1[128 + lane];  x1[o + 128 + lane] = r2 > 0 ? r2 : 0;
    float r3 = acc3 + b1[192 + lane];  x1[o + 192 + lane] = r3 > 0 ? r3 : 0;
}

__global__ __launch_bounds__(256) void k_aggr2(int n, const int* __restrict__ rowptr,
    const int* __restrict__ col, const float* __restrict__ h2,
    const float* __restrict__ a_src, const float* __restrict__ a_dst,
    const float* __restrict__ b2, float* __restrict__ x2)
{
    int v = (blockIdx.x * blockDim.x + threadIdx.x) >> 6;
    int lane = threadIdx.x & 63;
    if (v >= n) return;
    int beg = rowptr[v], end = rowptr[v + 1];
    float ad = a_dst[v];
    float m = -1e30f;
    for (int i = beg; i < end; ++i) {
        float e = lrelu(a_src[col[i]] + ad);
        m = fmaxf(m, e);
    }
    float s = 0;
    for (int i = beg; i < end; ++i) {
        float e = lrelu(a_src[col[i]] + ad);
        s += __expf(e - m);
    }
    float inv = 1.0f / (s + 1e-16f);
    float acc = 0;
    for (int i = beg; i < end; ++i) {
        int sidx = col[i];
        float e = lrelu(a_src[sidx] + ad);
        float al = __expf(e - m) * inv;
        acc += h2[(size_t)sidx * HD + lane] * al;
    }
    x2[(size_t)v * HD + lane] = acc + b2[lane];
}

// ---------------------------------------------------------------- GRU gates (h0 = 0 => gh = bhh)
__global__ __launch_bounds__(256) void k_gru_gates(int n, const float* __restrict__ gi,
    const float* __restrict__ bih, const float* __restrict__ bhh, float* __restrict__ hout)
{
    int t = blockIdx.x * blockDim.x + threadIdx.x;
    if (t >= n * HD) return;
    int v = t >> 6, u = t & 63;
    const float* g = gi + (size_t)v * G3;
    float r  = sigm(g[u]        + bih[u]        + bhh[u]);
    float z  = sigm(g[64 + u]   + bih[64 + u]   + bhh[64 + u]);
    float nn = tanhf(g[128 + u] + bih[128 + u]  + r * bhh[128 + u]);
    hout[t] = (1.0f - z) * nn;
}

// ---------------------------------------------------------------- final FC (wave per node)
__global__ __launch_bounds__(256) void k_fc(int n, const float* __restrict__ h,
    const float* __restrict__ fcW, const float* __restrict__ fcb, float* __restrict__ out)
{
    int v = (blockIdx.x * blockDim.x + threadIdx.x) >> 6;
    int lane = threadIdx.x & 63;
    if (v >= n) return;
    float x = h[(size_t)v * HD + lane];
    float p0 = x * fcW[lane];
    float p1 = x * fcW[64 + lane];
    float p2 = x * fcW[128 + lane];
    #pragma unroll
    for (int off = 32; off > 0; off >>= 1) {
        p0 += __shfl_down(p0, off);
        p1 += __shfl_down(p1, off);
        p2 += __shfl_down(p2, off);
    }
    if (lane == 0) {
        out[(size_t)v * 3 + 0] = p0 + fcb[0];
        out[(size_t)v * 3 + 1] = p1 + fcb[1];
        out[(size_t)v * 3 + 2] = p2 + fcb[2];
    }
}

// ----------------------------------------------------------------
extern "C" void kernel_launch(void* const* d_in, const int* in_sizes, int n_in,
                              void* d_out, int out_size, void* d_ws, size_t ws_size,
                              hipStream_t stream)
{
    const float* x    = (const float*)d_in[0];
    const int*   eidx = (const int*)d_in[1];
    const float* W1   = (const float*)d_in[2];
    const float* aS1  = (const float*)d_in[3];
    const float* aD1  = (const float*)d_in[4];
    const float* b1   = (const float*)d_in[5];
    const float* W2   = (const float*)d_in[6];
    const float* aS2  = (const float*)d_in[7];
    const float* aD2  = (const float*)d_in[8];
    const float* b2   = (const float*)d_in[9];
    const float* Wih0 = (const float*)d_in[10];
    const float* bih0 = (const float*)d_in[12];
    const float* bhh0 = (const float*)d_in[13];
    const float* Wih1 = (const float*)d_in[14];
    const float* bih1 = (const float*)d_in[16];
    const float* bhh1 = (const float*)d_in[17];
    const float* fcW  = (const float*)d_in[18];
    const float* fcb  = (const float*)d_in[19];
    float* out = (float*)d_out;

    const int N = in_sizes[0] / N_FIN;
    const int E = in_sizes[1] / 2;
    const int* esrc = eidx;
    const int* edst = eidx + E;

    // ---- workspace layout (fp32 elements) ----
    float* f   = (float*)d_ws;
    float* h1  = f;                        // N*256   (aliased later by gi/hg)
    float* x1  = h1 + (size_t)N * C1;      // N*256
    float* g2  = x1 + (size_t)N * C1;      // N*64    GAT2 features
    float* x2  = g2 + (size_t)N * HD;      // N*64    GAT2 output (aliased later by hg2)
    float* as1 = x2 + (size_t)N * HD;      // N*4
    float* ad1 = as1 + (size_t)N * NH;     // N*4
    float* as2 = ad1 + (size_t)N * NH;     // N
    float* ad2 = as2 + (size_t)N;          // N
    int* ip     = (int*)(ad2 + N);
    int* deg    = ip;                      // N
    int* rowptr = deg + N;                 // N+1
    int* cursor = rowptr + N + 1;          // N
    int* incl   = cursor + N;              // N
    int* bsum   = incl + N;                // <=256
    int* col    = bsum + 256;              // E+N
    float* gi  = f;                        // N*192 (h1 dead by then)
    float* hg  = f + (size_t)N * G3;       // N*64  (tail of h1 region)
    float* hg2 = x2;                       // N*64  (x2 dead by then)

    const int nbN   = (N + 255) / 256;
    const int nbE   = (E + 255) / 256;
    const int nbEN  = (E + N + 255) / 256;
    const int nbW   = (N + 3) / 4;         // wave-per-node kernels, 4 waves/block
    const int nbNU  = (N * HD + 255) / 256;
    const int NB    = (N + 1023) / 1024;

    // ---- CSR build ----
    k_deg_init<<<nbN, 256, 0, stream>>>(N, deg);
    k_hist<<<nbE, 256, 0, stream>>>(E, edst, deg);
    k_scan_block<<<NB, 1024, 0, stream>>>(N, deg, incl, bsum);
    k_scan_bsum<<<1, 64, 0, stream>>>(NB, bsum);
    k_rowptr<<<nbN, 256, 0, stream>>>(N, incl, bsum, rowptr);
    k_cursor<<<nbN, 256, 0, stream>>>(N, rowptr, cursor);
    k_fill<<<nbEN, 256, 0, stream>>>(E, N, esrc, edst, cursor, col);

    // ---- GAT layer 1 ----
    sgemm_nn<<<dim3((N + 63) / 64, C1 / 64), 256, 0, stream>>>(N, C1, N_FIN, x, N_FIN, W1, C1, h1, C1);
    k_att1<<<nbW, 256, 0, stream>>>(N, h1, aS1, aD1, as1, ad1);
    k_aggr1<<<nbW, 256, 0, stream>>>(N, rowptr, col, h1, as1, ad1, b1, x1);

    // ---- GAT layer 2 ----
    sgemm_nn<<<dim3((N + 63) / 64, HD / 64), 256, 0, stream>>>(N, HD, C1, x1, C1, W2, HD, g2, HD);
    k_att2<<<nbW, 256, 0, stream>>>(N, g2, aS2, aD2, as2, ad2);
    k_aggr2<<<nbW, 256, 0, stream>>>(N, rowptr, col, g2, as2, ad2, b2, x2);

    // ---- GRU layer 0: gi = x2 @ Wih0^T ; gates ----
    sgemm_nt<<<dim3((N + 63) / 64, G3 / 64), 256, 0, stream>>>(N, G3, HD, x2, HD, Wih0, HD, gi, G3);
    k_gru_gates<<<nbNU, 256, 0, stream>>>(N, gi, bih0, bhh0, hg);

    // ---- GRU layer 1 ----
    sgemm_nt<<<dim3((N + 63) / 64, G3 / 64), 256, 0, stream>>>(N, G3, HD, hg, HD, Wih1, HD, gi, G3);
    k_gru_gates<<<nbNU, 256, 0, stream>>>(N, gi, bih1, bhh1, hg2);

    // ---- FC ----
    k_fc<<<nbW, 256, 0, stream>>>(N, hg2, fcW, fcb, out);

    (void)n_in; (void)out_size; (void)ws_size;
}

// Round 3
// 831.990 us; speedup vs baseline: 1.3181x; 1.3181x over previous
//
#include <hip/hip_runtime.h>
#include <math.h>

#define N_FIN 128
#define C1    256   // HEADS*HID
#define NH    4
#define HD    64
#define G3    192   // 3*HID

static __device__ __forceinline__ float lrelu(float x) { return x >= 0.0f ? x : 0.2f * x; }
static __device__ __forceinline__ float sigm(float x)  { return 1.0f / (1.0f + __expf(-x)); }

// ---------------------------------------------------------------- CSR build
__global__ __launch_bounds__(256) void k_deg_init(int n, int* __restrict__ deg)
{
    int i = blockIdx.x * blockDim.x + threadIdx.x;
    if (i < n) deg[i] = 1;  // self-loop
}

__global__ __launch_bounds__(256) void k_hist(int E, const int* __restrict__ edst, int* __restrict__ deg)
{
    int e = blockIdx.x * blockDim.x + threadIdx.x;
    if (e < E) atomicAdd(&deg[edst[e]], 1);
}

__global__ __launch_bounds__(1024) void k_scan_block(int n, const int* __restrict__ deg,
                                                     int* __restrict__ incl, int* __restrict__ bsum)
{
    __shared__ int sh[1024];
    int t = threadIdx.x;
    int i = blockIdx.x * 1024 + t;
    sh[t] = (i < n) ? deg[i] : 0;
    __syncthreads();
    #pragma unroll
    for (int off = 1; off < 1024; off <<= 1) {
        int u = (t >= off) ? sh[t - off] : 0;
        __syncthreads();
        sh[t] += u;
        __syncthreads();
    }
    if (i < n) incl[i] = sh[t];
    if (t == 1023) bsum[blockIdx.x] = sh[1023];
}

__global__ void k_scan_bsum(int nb, int* __restrict__ bsum)
{
    if (threadIdx.x == 0 && blockIdx.x == 0) {
        int run = 0;
        for (int b = 0; b < nb; ++b) { int v = bsum[b]; bsum[b] = run; run += v; }
    }
}

__global__ __launch_bounds__(256) void k_rowptr(int n, const int* __restrict__ incl,
                                                const int* __restrict__ bsum, int* __restrict__ rowptr)
{
    int i = blockIdx.x * blockDim.x + threadIdx.x;
    if (i < n) rowptr[i + 1] = incl[i] + bsum[i >> 10];
    if (i == 0) rowptr[0] = 0;
}

__global__ __launch_bounds__(256) void k_cursor(int n, const int* __restrict__ rowptr, int* __restrict__ cursor)
{
    int i = blockIdx.x * blockDim.x + threadIdx.x;
    if (i < n) cursor[i] = rowptr[i];
}

__global__ __launch_bounds__(256) void k_fill(int E, int n, const int* __restrict__ esrc,
                                              const int* __restrict__ edst,
                                              int* __restrict__ cursor, int* __restrict__ col)
{
    int t = blockIdx.x * blockDim.x + threadIdx.x;
    if (t < E) {
        int p = atomicAdd(&cursor[edst[t]], 1);
        col[p] = esrc[t];
    } else if (t < E + n) {
        int v = t - E;
        int p = atomicAdd(&cursor[v], 1);
        col[p] = v;   // self-loop
    }
}

// ---------------------------------------------------------------- fp32 GEMM (NN): C[M,N] = A[M,K] @ B[K,N]
__global__ __launch_bounds__(256) void sgemm_nn(int M, int N, int K,
    const float* __restrict__ A, int lda, const float* __restrict__ B, int ldb,
    float* __restrict__ C, int ldc)
{
    __shared__ float As[16][65];
    __shared__ float Bs[16][64];
    const int tid = threadIdx.x;
    const int tx = tid & 15, ty = tid >> 4;
    const int row0 = blockIdx.x * 64, col0 = blockIdx.y * 64;
    const int ar = tid >> 2, akq = (tid & 3) << 2;
    const int bk = tid >> 4, bc = (tid & 15) << 2;
    float acc[4][4] = {};
    for (int k0 = 0; k0 < K; k0 += 16) {
        int arow = row0 + ar; arow = arow < M ? arow : M - 1;
        float4 av = *reinterpret_cast<const float4*>(A + (size_t)arow * lda + k0 + akq);
        float4 bv = *reinterpret_cast<const float4*>(B + (size_t)(k0 + bk) * ldb + col0 + bc);
        As[akq + 0][ar] = av.x; As[akq + 1][ar] = av.y; As[akq + 2][ar] = av.z; As[akq + 3][ar] = av.w;
        *reinterpret_cast<float4*>(&Bs[bk][bc]) = bv;
        __syncthreads();
        #pragma unroll
        for (int k = 0; k < 16; ++k) {
            float a0 = As[k][ty * 4 + 0], a1 = As[k][ty * 4 + 1];
            float a2 = As[k][ty * 4 + 2], a3 = As[k][ty * 4 + 3];
            float4 b4 = *reinterpret_cast<const float4*>(&Bs[k][tx * 4]);
            acc[0][0] += a0 * b4.x; acc[0][1] += a0 * b4.y; acc[0][2] += a0 * b4.z; acc[0][3] += a0 * b4.w;
            acc[1][0] += a1 * b4.x; acc[1][1] += a1 * b4.y; acc[1][2] += a1 * b4.z; acc[1][3] += a1 * b4.w;
            acc[2][0] += a2 * b4.x; acc[2][1] += a2 * b4.y; acc[2][2] += a2 * b4.z; acc[2][3] += a2 * b4.w;
            acc[3][0] += a3 * b4.x; acc[3][1] += a3 * b4.y; acc[3][2] += a3 * b4.z; acc[3][3] += a3 * b4.w;
        }
        __syncthreads();
    }
    #pragma unroll
    for (int i = 0; i < 4; ++i) {
        int r = row0 + ty * 4 + i;
        if (r < M) {
            float4 o = make_float4(acc[i][0], acc[i][1], acc[i][2], acc[i][3]);
            *reinterpret_cast<float4*>(C + (size_t)r * ldc + col0 + tx * 4) = o;
        }
    }
}

// ---------------------------------------------------------------- fp32 GEMM (NT): C[M,N] = A[M,K] @ B[N,K]^T
__global__ __launch_bounds__(256) void sgemm_nt(int M, int N, int K,
    const float* __restrict__ A, int lda, const float* __restrict__ B, int ldb,
    float* __restrict__ C, int ldc)
{
    __shared__ float As[16][65];
    __shared__ float Bs[16][65];
    const int tid = threadIdx.x;
    const int tx = tid & 15, ty = tid >> 4;
    const int row0 = blockIdx.x * 64, col0 = blockIdx.y * 64;
    const int ar = tid >> 2, akq = (tid & 3) << 2;  // also used for B (row-of-B = output col)
    float acc[4][4] = {};
    for (int k0 = 0; k0 < K; k0 += 16) {
        int arow = row0 + ar; arow = arow < M ? arow : M - 1;
        float4 av = *reinterpret_cast<const float4*>(A + (size_t)arow * lda + k0 + akq);
        float4 bv = *reinterpret_cast<const float4*>(B + (size_t)(col0 + ar) * ldb + k0 + akq);
        As[akq + 0][ar] = av.x; As[akq + 1][ar] = av.y; As[akq + 2][ar] = av.z; As[akq + 3][ar] = av.w;
        Bs[akq + 0][ar] = bv.x; Bs[akq + 1][ar] = bv.y; Bs[akq + 2][ar] = bv.z; Bs[akq + 3][ar] = bv.w;
        __syncthreads();
        #pragma unroll
        for (int k = 0; k < 16; ++k) {
            float a0 = As[k][ty * 4 + 0], a1 = As[k][ty * 4 + 1];
            float a2 = As[k][ty * 4 + 2], a3 = As[k][ty * 4 + 3];
            float b0 = Bs[k][tx * 4 + 0], b1 = Bs[k][tx * 4 + 1];
            float b2 = Bs[k][tx * 4 + 2], b3 = Bs[k][tx * 4 + 3];
            acc[0][0] += a0 * b0; acc[0][1] += a0 * b1; acc[0][2] += a0 * b2; acc[0][3] += a0 * b3;
            acc[1][0] += a1 * b0; acc[1][1] += a1 * b1; acc[1][2] += a1 * b2; acc[1][3] += a1 * b3;
            acc[2][0] += a2 * b0; acc[2][1] += a2 * b1; acc[2][2] += a2 * b2; acc[2][3] += a2 * b3;
            acc[3][0] += a3 * b0; acc[3][1] += a3 * b1; acc[3][2] += a3 * b2; acc[3][3] += a3 * b3;
        }
        __syncthreads();
    }
    #pragma unroll
    for (int i = 0; i < 4; ++i) {
        int r = row0 + ty * 4 + i;
        if (r < M) {
            float4 o = make_float4(acc[i][0], acc[i][1], acc[i][2], acc[i][3]);
            *reinterpret_cast<float4*>(C + (size_t)r * ldc + col0 + tx * 4) = o;
        }
    }
}

// ---------------------------------------------------------------- attention coefficients
__global__ __launch_bounds__(256) void k_att1(int n, const float* __restrict__ h1,
    const float* __restrict__ att_src, const float* __restrict__ att_dst,
    float* __restrict__ a_src, float* __restrict__ a_dst)
{
    int v = (blockIdx.x * blockDim.x + threadIdx.x) >> 6;
    int lane = threadIdx.x & 63;
    if (v >= n) return;
    const float* hr = h1 + (size_t)v * C1;
    #pragma unroll
    for (int h = 0; h < NH; ++h) {
        float x = hr[h * HD + lane];
        float ps = x * att_src[h * HD + lane];
        float pd = x * att_dst[h * HD + lane];
        #pragma unroll
        for (int off = 32; off > 0; off >>= 1) {
            ps += __shfl_down(ps, off);
            pd += __shfl_down(pd, off);
        }
        if (lane == 0) { a_src[v * NH + h] = ps; a_dst[v * NH + h] = pd; }
    }
}

__global__ __launch_bounds__(256) void k_att2(int n, const float* __restrict__ h2,
    const float* __restrict__ att_src, const float* __restrict__ att_dst,
    float* __restrict__ a_src, float* __restrict__ a_dst)
{
    int v = (blockIdx.x * blockDim.x + threadIdx.x) >> 6;
    int lane = threadIdx.x & 63;
    if (v >= n) return;
    float x = h2[(size_t)v * HD + lane];
    float ps = x * att_src[lane];
    float pd = x * att_dst[lane];
    #pragma unroll
    for (int off = 32; off > 0; off >>= 1) {
        ps += __shfl_down(ps, off);
        pd += __shfl_down(pd, off);
    }
    if (lane == 0) { a_src[v] = ps; a_dst[v] = pd; }
}

// ---------------------------------------------------------------- GAT1 aggregation
// wave per dst node; 4x16-lane subgroups = 4 heads; lane handles float4 slice of its head.
// 2 passes: (max) then (exp + denom + weighted accumulate), normalize at end.
__global__ __launch_bounds__(256) void k_aggr1(int n, const int* __restrict__ rowptr,
    const int* __restrict__ col, const float* __restrict__ h1,
    const float* __restrict__ a_src, const float* __restrict__ a_dst,
    const float* __restrict__ b1, float* __restrict__ x1)
{
    int v = (blockIdx.x * blockDim.x + threadIdx.x) >> 6;
    int lane = threadIdx.x & 63;
    if (v >= n) return;
    const int sub = lane >> 4;       // head
    const int l   = lane & 15;       // float4 slot within head
    int beg = rowptr[v], end = rowptr[v + 1];
    float ad = a_dst[(size_t)v * NH + sub];

    float m = -1e30f;
    for (int i = beg; i < end; ++i) {
        float as = a_src[(size_t)col[i] * NH + sub];
        m = fmaxf(m, lrelu(as + ad));
    }

    float sum = 0.0f;
    float4 acc = make_float4(0.f, 0.f, 0.f, 0.f);
    for (int i = beg; i < end; ++i) {
        int s = col[i];
        float as = a_src[(size_t)s * NH + sub];
        float p = __expf(lrelu(as + ad) - m);
        sum += p;
        float4 h4 = *reinterpret_cast<const float4*>(h1 + (size_t)s * C1 + sub * HD + l * 4);
        acc.x += p * h4.x; acc.y += p * h4.y; acc.z += p * h4.z; acc.w += p * h4.w;
    }
    float inv = 1.0f / (sum + 1e-16f);
    float4 bb = *reinterpret_cast<const float4*>(b1 + sub * HD + l * 4);
    float4 r;
    r.x = acc.x * inv + bb.x; r.y = acc.y * inv + bb.y;
    r.z = acc.z * inv + bb.z; r.w = acc.w * inv + bb.w;
    r.x = r.x > 0.f ? r.x : 0.f; r.y = r.y > 0.f ? r.y : 0.f;
    r.z = r.z > 0.f ? r.z : 0.f; r.w = r.w > 0.f ? r.w : 0.f;
    *reinterpret_cast<float4*>(x1 + (size_t)v * C1 + sub * HD + l * 4) = r;
}

// ---------------------------------------------------------------- GAT2 aggregation
// wave per dst node; 4x16-lane subgroups stride the edge list; lane&15 indexes float4 of HD=64.
__global__ __launch_bounds__(256) void k_aggr2(int n, const int* __restrict__ rowptr,
    const int* __restrict__ col, const float* __restrict__ h2,
    const float* __restrict__ a_src, const float* __restrict__ a_dst,
    const float* __restrict__ b2, float* __restrict__ x2)
{
    int v = (blockIdx.x * blockDim.x + threadIdx.x) >> 6;
    int lane = threadIdx.x & 63;
    if (v >= n) return;
    const int sub = lane >> 4;
    const int l   = lane & 15;
    int beg = rowptr[v], end = rowptr[v + 1];
    float ad = a_dst[v];

    float m = -1e30f;
    for (int i = beg + sub; i < end; i += 4)
        m = fmaxf(m, lrelu(a_src[col[i]] + ad));
    m = fmaxf(m, __shfl_xor(m, 16));
    m = fmaxf(m, __shfl_xor(m, 32));

    float sum = 0.0f;
    float4 acc = make_float4(0.f, 0.f, 0.f, 0.f);
    for (int i = beg + sub; i < end; i += 4) {
        int s = col[i];
        float p = __expf(lrelu(a_src[s] + ad) - m);
        sum += p;
        float4 h4 = *reinterpret_cast<const float4*>(h2 + (size_t)s * HD + l * 4);
        acc.x += p * h4.x; acc.y += p * h4.y; acc.z += p * h4.z; acc.w += p * h4.w;
    }
    sum += __shfl_xor(sum, 16); sum += __shfl_xor(sum, 32);
    acc.x += __shfl_xor(acc.x, 16); acc.x += __shfl_xor(acc.x, 32);
    acc.y += __shfl_xor(acc.y, 16); acc.y += __shfl_xor(acc.y, 32);
    acc.z += __shfl_xor(acc.z, 16); acc.z += __shfl_xor(acc.z, 32);
    acc.w += __shfl_xor(acc.w, 16); acc.w += __shfl_xor(acc.w, 32);

    if (sub == 0) {
        float inv = 1.0f / (sum + 1e-16f);
        float4 bb = *reinterpret_cast<const float4*>(b2 + l * 4);
        float4 r;
        r.x = acc.x * inv + bb.x; r.y = acc.y * inv + bb.y;
        r.z = acc.z * inv + bb.z; r.w = acc.w * inv + bb.w;
        *reinterpret_cast<float4*>(x2 + (size_t)v * HD + l * 4) = r;
    }
}

// ---------------------------------------------------------------- GRU gates (h0 = 0 => gh = bhh)
__global__ __launch_bounds__(256) void k_gru_gates(int n, const float* __restrict__ gi,
    const float* __restrict__ bih, const float* __restrict__ bhh, float* __restrict__ hout)
{
    int t = blockIdx.x * blockDim.x + threadIdx.x;
    if (t >= n * HD) return;
    int v = t >> 6, u = t & 63;
    const float* g = gi + (size_t)v * G3;
    float r  = sigm(g[u]        + bih[u]        + bhh[u]);
    float z  = sigm(g[64 + u]   + bih[64 + u]   + bhh[64 + u]);
    float nn = tanhf(g[128 + u] + bih[128 + u]  + r * bhh[128 + u]);
    hout[t] = (1.0f - z) * nn;
}

// ---------------------------------------------------------------- final FC (wave per node)
__global__ __launch_bounds__(256) void k_fc(int n, const float* __restrict__ h,
    const float* __restrict__ fcW, const float* __restrict__ fcb, float* __restrict__ out)
{
    int v = (blockIdx.x * blockDim.x + threadIdx.x) >> 6;
    int lane = threadIdx.x & 63;
    if (v >= n) return;
    float x = h[(size_t)v * HD + lane];
    float p0 = x * fcW[lane];
    float p1 = x * fcW[64 + lane];
    float p2 = x * fcW[128 + lane];
    #pragma unroll
    for (int off = 32; off > 0; off >>= 1) {
        p0 += __shfl_down(p0, off);
        p1 += __shfl_down(p1, off);
        p2 += __shfl_down(p2, off);
    }
    if (lane == 0) {
        out[(size_t)v * 3 + 0] = p0 + fcb[0];
        out[(size_t)v * 3 + 1] = p1 + fcb[1];
        out[(size_t)v * 3 + 2] = p2 + fcb[2];
    }
}

// ----------------------------------------------------------------
extern "C" void kernel_launch(void* const* d_in, const int* in_sizes, int n_in,
                              void* d_out, int out_size, void* d_ws, size_t ws_size,
                              hipStream_t stream)
{
    const float* x    = (const float*)d_in[0];
    const int*   eidx = (const int*)d_in[1];
    const float* W1   = (const float*)d_in[2];
    const float* aS1  = (const float*)d_in[3];
    const float* aD1  = (const float*)d_in[4];
    const float* b1   = (const float*)d_in[5];
    const float* W2   = (const float*)d_in[6];
    const float* aS2  = (const float*)d_in[7];
    const float* aD2  = (const float*)d_in[8];
    const float* b2   = (const float*)d_in[9];
    const float* Wih0 = (const float*)d_in[10];
    const float* bih0 = (const float*)d_in[12];
    const float* bhh0 = (const float*)d_in[13];
    const float* Wih1 = (const float*)d_in[14];
    const float* bih1 = (const float*)d_in[16];
    const float* bhh1 = (const float*)d_in[17];
    const float* fcW  = (const float*)d_in[18];
    const float* fcb  = (const float*)d_in[19];
    float* out = (float*)d_out;

    const int N = in_sizes[0] / N_FIN;
    const int E = in_sizes[1] / 2;
    const int* esrc = eidx;
    const int* edst = eidx + E;

    // ---- workspace layout (fp32 elements) ----
    float* f   = (float*)d_ws;
    float* h1  = f;                        // N*256   (aliased later by gi/hg)
    float* x1  = h1 + (size_t)N * C1;      // N*256
    float* g2  = x1 + (size_t)N * C1;      // N*64    GAT2 features
    float* x2  = g2 + (size_t)N * HD;      // N*64    GAT2 output (aliased later by hg2)
    float* as1 = x2 + (size_t)N * HD;      // N*4
    float* ad1 = as1 + (size_t)N * NH;     // N*4
    float* as2 = ad1 + (size_t)N * NH;     // N
    float* ad2 = as2 + (size_t)N;          // N
    int* ip     = (int*)(ad2 + N);
    int* deg    = ip;                      // N
    int* rowptr = deg + N;                 // N+1
    int* cursor = rowptr + N + 1;          // N
    int* incl   = cursor + N;              // N
    int* bsum   = incl + N;                // <=256
    int* col    = bsum + 256;              // E+N
    float* gi  = f;                        // N*192 (h1 dead by then)
    float* hg  = f + (size_t)N * G3;       // N*64  (tail of h1 region)
    float* hg2 = x2;                       // N*64  (x2 dead by then)

    const int nbN   = (N + 255) / 256;
    const int nbE   = (E + 255) / 256;
    const int nbEN  = (E + N + 255) / 256;
    const int nbW   = (N + 3) / 4;         // wave-per-node kernels, 4 waves/block
    const int nbNU  = (N * HD + 255) / 256;
    const int NB    = (N + 1023) / 1024;

    // ---- CSR build ----
    k_deg_init<<<nbN, 256, 0, stream>>>(N, deg);
    k_hist<<<nbE, 256, 0, stream>>>(E, edst, deg);
    k_scan_block<<<NB, 1024, 0, stream>>>(N, deg, incl, bsum);
    k_scan_bsum<<<1, 64, 0, stream>>>(NB, bsum);
    k_rowptr<<<nbN, 256, 0, stream>>>(N, incl, bsum, rowptr);
    k_cursor<<<nbN, 256, 0, stream>>>(N, rowptr, cursor);
    k_fill<<<nbEN, 256, 0, stream>>>(E, N, esrc, edst, cursor, col);

    // ---- GAT layer 1 ----
    sgemm_nn<<<dim3((N + 63) / 64, C1 / 64), 256, 0, stream>>>(N, C1, N_FIN, x, N_FIN, W1, C1, h1, C1);
    k_att1<<<nbW, 256, 0, stream>>>(N, h1, aS1, aD1, as1, ad1);
    k_aggr1<<<nbW, 256, 0, stream>>>(N, rowptr, col, h1, as1, ad1, b1, x1);

    // ---- GAT layer 2 ----
    sgemm_nn<<<dim3((N + 63) / 64, HD / 64), 256, 0, stream>>>(N, HD, C1, x1, C1, W2, HD, g2, HD);
    k_att2<<<nbW, 256, 0, stream>>>(N, g2, aS2, aD2, as2, ad2);
    k_aggr2<<<nbW, 256, 0, stream>>>(N, rowptr, col, g2, as2, ad2, b2, x2);

    // ---- GRU layer 0: gi = x2 @ Wih0^T ; gates ----
    sgemm_nt<<<dim3((N + 63) / 64, G3 / 64), 256, 0, stream>>>(N, G3, HD, x2, HD, Wih0, HD, gi, G3);
    k_gru_gates<<<nbNU, 256, 0, stream>>>(N, gi, bih0, bhh0, hg);

    // ---- GRU layer 1 ----
    sgemm_nt<<<dim3((N + 63) / 64, G3 / 64), 256, 0, stream>>>(N, G3, HD, hg, HD, Wih1, HD, gi, G3);
    k_gru_gates<<<nbNU, 256, 0, stream>>>(N, gi, bih1, bhh1, hg2);

    // ---- FC ----
    k_fc<<<nbW, 256, 0, stream>>>(N, hg2, fcW, fcb, out);

    (void)n_in; (void)out_size; (void)ws_size;
}

// Round 4
// 766.309 us; speedup vs baseline: 1.4311x; 1.0857x over previous
//
#include <hip/hip_runtime.h>
#include <math.h>

#define N_FIN 128
#define C1    256   // HEADS*HID
#define NH    4
#define HD    64
#define G3    192   // 3*HID

static __device__ __forceinline__ float lrelu(float x) { return x >= 0.0f ? x : 0.2f * x; }
static __device__ __forceinline__ float sigm(float x)  { return 1.0f / (1.0f + __expf(-x)); }

// ---------------------------------------------------------------- CSR build
__global__ __launch_bounds__(256) void k_deg_init(int n, int* __restrict__ deg)
{
    int i = blockIdx.x * blockDim.x + threadIdx.x;
    if (i < n) deg[i] = 1;  // self-loop
}

__global__ __launch_bounds__(256) void k_hist(int E, const int* __restrict__ edst, int* __restrict__ deg)
{
    int e = blockIdx.x * blockDim.x + threadIdx.x;
    if (e < E) atomicAdd(&deg[edst[e]], 1);
}

__global__ __launch_bounds__(1024) void k_scan_block(int n, const int* __restrict__ deg,
                                                     int* __restrict__ incl, int* __restrict__ bsum)
{
    __shared__ int sh[1024];
    int t = threadIdx.x;
    int i = blockIdx.x * 1024 + t;
    sh[t] = (i < n) ? deg[i] : 0;
    __syncthreads();
    #pragma unroll
    for (int off = 1; off < 1024; off <<= 1) {
        int u = (t >= off) ? sh[t - off] : 0;
        __syncthreads();
        sh[t] += u;
        __syncthreads();
    }
    if (i < n) incl[i] = sh[t];
    if (t == 1023) bsum[blockIdx.x] = sh[1023];
}

__global__ void k_scan_bsum(int nb, int* __restrict__ bsum)
{
    if (threadIdx.x == 0 && blockIdx.x == 0) {
        int run = 0;
        for (int b = 0; b < nb; ++b) { int v = bsum[b]; bsum[b] = run; run += v; }
    }
}

__global__ __launch_bounds__(256) void k_rowptr(int n, const int* __restrict__ incl,
                                                const int* __restrict__ bsum, int* __restrict__ rowptr)
{
    int i = blockIdx.x * blockDim.x + threadIdx.x;
    if (i < n) rowptr[i + 1] = incl[i] + bsum[i >> 10];
    if (i == 0) rowptr[0] = 0;
}

__global__ __launch_bounds__(256) void k_cursor(int n, const int* __restrict__ rowptr, int* __restrict__ cursor)
{
    int i = blockIdx.x * blockDim.x + threadIdx.x;
    if (i < n) cursor[i] = rowptr[i];
}

__global__ __launch_bounds__(256) void k_fill(int E, int n, const int* __restrict__ esrc,
                                              const int* __restrict__ edst,
                                              int* __restrict__ cursor, int* __restrict__ col)
{
    int t = blockIdx.x * blockDim.x + threadIdx.x;
    if (t < E) {
        int p = atomicAdd(&cursor[edst[t]], 1);
        col[p] = esrc[t];
    } else if (t < E + n) {
        int v = t - E;
        int p = atomicAdd(&cursor[v], 1);
        col[p] = v;   // self-loop
    }
}

// ---------------------------------------------------------------- big-tile fp32 GEMM
// BM=128, BK=16, 256 threads (16x16), micro-tile 8 x TN.
// TRANSB=false: C[M,N] = A[M,K] @ B[K,N];  TRANSB=true: C = A @ B[N,K]^T.
// Requires: N % BN == 0, K % 16 == 0 (holds for all our shapes).
template<int BN, int TN, bool TRANSB>
__global__ __launch_bounds__(256) void sgemm_big(int M, int N, int K,
    const float* __restrict__ A, int lda, const float* __restrict__ B, int ldb,
    float* __restrict__ C, int ldc)
{
    __shared__ float As[16][132];      // transposed A-tile, padded (132 % 4 == 0 keeps f4 alignment)
    __shared__ float Bs[16][BN + 4];
    const int tid = threadIdx.x;
    const int tx = tid & 15, ty = tid >> 4;
    const int row0 = blockIdx.x * 128, col0 = blockIdx.y * BN;
    float acc[8][TN] = {};

    for (int k0 = 0; k0 < K; k0 += 16) {
        // A-tile: 128x16 = 512 float4, 2 per thread, stored transposed As[k][m]
        #pragma unroll
        for (int u = 0; u < 2; ++u) {
            int i = tid + u * 256;
            int r = i >> 2, kq = (i & 3) << 2;
            int arow = row0 + r; arow = arow < M ? arow : M - 1;
            float4 av = *reinterpret_cast<const float4*>(A + (size_t)arow * lda + k0 + kq);
            As[kq + 0][r] = av.x; As[kq + 1][r] = av.y; As[kq + 2][r] = av.z; As[kq + 3][r] = av.w;
        }
        // B-tile -> Bs[k][n]
        if (TRANSB) {
            // B[N,K]: BN rows x 4 float4 along K; BN=64 -> 256 f4 -> 1 per thread
            int nn = tid >> 2, kq = (tid & 3) << 2;
            float4 bv = *reinterpret_cast<const float4*>(B + (size_t)(col0 + nn) * ldb + k0 + kq);
            Bs[kq + 0][nn] = bv.x; Bs[kq + 1][nn] = bv.y; Bs[kq + 2][nn] = bv.z; Bs[kq + 3][nn] = bv.w;
        } else {
            #pragma unroll
            for (int u = 0; u < BN / 64; ++u) {
                int i = tid + u * 256;
                int kk = i / (BN / 4), n4 = (i % (BN / 4)) * 4;
                float4 bv = *reinterpret_cast<const float4*>(B + (size_t)(k0 + kk) * ldb + col0 + n4);
                *reinterpret_cast<float4*>(&Bs[kk][n4]) = bv;
            }
        }
        __syncthreads();
        #pragma unroll
        for (int k = 0; k < 16; ++k) {
            float a[8], b[TN];
            *reinterpret_cast<float4*>(&a[0]) = *reinterpret_cast<const float4*>(&As[k][ty * 8]);
            *reinterpret_cast<float4*>(&a[4]) = *reinterpret_cast<const float4*>(&As[k][ty * 8 + 4]);
            #pragma unroll
            for (int j = 0; j < TN; j += 4)
                *reinterpret_cast<float4*>(&b[j]) = *reinterpret_cast<const float4*>(&Bs[k][tx * TN + j]);
            #pragma unroll
            for (int i2 = 0; i2 < 8; ++i2)
                #pragma unroll
                for (int j = 0; j < TN; ++j)
                    acc[i2][j] += a[i2] * b[j];
        }
        __syncthreads();
    }
    #pragma unroll
    for (int i2 = 0; i2 < 8; ++i2) {
        int r = row0 + ty * 8 + i2;
        if (r < M) {
            #pragma unroll
            for (int j = 0; j < TN; j += 4) {
                float4 o = make_float4(acc[i2][j], acc[i2][j + 1], acc[i2][j + 2], acc[i2][j + 3]);
                *reinterpret_cast<float4*>(C + (size_t)r * ldc + col0 + tx * TN + j) = o;
            }
        }
    }
}

// ---------------------------------------------------------------- attention coefficients
__global__ __launch_bounds__(256) void k_att1(int n, const float* __restrict__ h1,
    const float* __restrict__ att_src, const float* __restrict__ att_dst,
    float* __restrict__ a_src, float* __restrict__ a_dst)
{
    int v = (blockIdx.x * blockDim.x + threadIdx.x) >> 6;
    int lane = threadIdx.x & 63;
    if (v >= n) return;
    const float* hr = h1 + (size_t)v * C1;
    #pragma unroll
    for (int h = 0; h < NH; ++h) {
        float x = hr[h * HD + lane];
        float ps = x * att_src[h * HD + lane];
        float pd = x * att_dst[h * HD + lane];
        #pragma unroll
        for (int off = 32; off > 0; off >>= 1) {
            ps += __shfl_down(ps, off);
            pd += __shfl_down(pd, off);
        }
        if (lane == 0) { a_src[v * NH + h] = ps; a_dst[v * NH + h] = pd; }
    }
}

__global__ __launch_bounds__(256) void k_att2(int n, const float* __restrict__ h2,
    const float* __restrict__ att_src, const float* __restrict__ att_dst,
    float* __restrict__ a_src, float* __restrict__ a_dst)
{
    int v = (blockIdx.x * blockDim.x + threadIdx.x) >> 6;
    int lane = threadIdx.x & 63;
    if (v >= n) return;
    float x = h2[(size_t)v * HD + lane];
    float ps = x * att_src[lane];
    float pd = x * att_dst[lane];
    #pragma unroll
    for (int off = 32; off > 0; off >>= 1) {
        ps += __shfl_down(ps, off);
        pd += __shfl_down(pd, off);
    }
    if (lane == 0) { a_src[v] = ps; a_dst[v] = pd; }
}

// ---------------------------------------------------------------- GAT1 aggregation
// Single pass, no max subtraction: logits are bounded (|e| << 50 for this data),
// softmax is shift-invariant so alpha is identical up to rounding; fminf(e,50)
// is a pure overflow guard that never triggers in-distribution.
// wave per dst node; 4x16-lane subgroups = 4 heads; lane handles float4 slice of its head.
__global__ __launch_bounds__(256) void k_aggr1(int n, const int* __restrict__ rowptr,
    const int* __restrict__ col, const float* __restrict__ h1,
    const float* __restrict__ a_src, const float* __restrict__ a_dst,
    const float* __restrict__ b1, float* __restrict__ x1)
{
    int v = (blockIdx.x * blockDim.x + threadIdx.x) >> 6;
    int lane = threadIdx.x & 63;
    if (v >= n) return;
    const int sub = lane >> 4;       // head
    const int l   = lane & 15;       // float4 slot within head
    int beg = rowptr[v], end = rowptr[v + 1];
    float ad = a_dst[(size_t)v * NH + sub];

    float sum = 0.0f;
    float4 acc = make_float4(0.f, 0.f, 0.f, 0.f);
    for (int i = beg; i < end; ++i) {
        int s = col[i];
        float as = a_src[(size_t)s * NH + sub];
        float p = __expf(fminf(lrelu(as + ad), 50.f));
        sum += p;
        float4 h4 = *reinterpret_cast<const float4*>(h1 + (size_t)s * C1 + sub * HD + l * 4);
        acc.x += p * h4.x; acc.y += p * h4.y; acc.z += p * h4.z; acc.w += p * h4.w;
    }
    float inv = 1.0f / (sum + 1e-16f);
    float4 bb = *reinterpret_cast<const float4*>(b1 + sub * HD + l * 4);
    float4 r;
    r.x = acc.x * inv + bb.x; r.y = acc.y * inv + bb.y;
    r.z = acc.z * inv + bb.z; r.w = acc.w * inv + bb.w;
    r.x = r.x > 0.f ? r.x : 0.f; r.y = r.y > 0.f ? r.y : 0.f;
    r.z = r.z > 0.f ? r.z : 0.f; r.w = r.w > 0.f ? r.w : 0.f;
    *reinterpret_cast<float4*>(x1 + (size_t)v * C1 + sub * HD + l * 4) = r;
}

// ---------------------------------------------------------------- GAT2 aggregation
// Single pass, no max (same argument as k_aggr1).
// wave per dst node; 4x16-lane subgroups stride the edge list; lane&15 indexes float4 of HD=64.
__global__ __launch_bounds__(256) void k_aggr2(int n, const int* __restrict__ rowptr,
    const int* __restrict__ col, const float* __restrict__ h2,
    const float* __restrict__ a_src, const float* __restrict__ a_dst,
    const float* __restrict__ b2, float* __restrict__ x2)
{
    int v = (blockIdx.x * blockDim.x + threadIdx.x) >> 6;
    int lane = threadIdx.x & 63;
    if (v >= n) return;
    const int sub = lane >> 4;
    const int l   = lane & 15;
    int beg = rowptr[v], end = rowptr[v + 1];
    float ad = a_dst[v];

    float sum = 0.0f;
    float4 acc = make_float4(0.f, 0.f, 0.f, 0.f);
    for (int i = beg + sub; i < end; i += 4) {
        int s = col[i];
        float p = __expf(fminf(lrelu(a_src[s] + ad), 50.f));
        sum += p;
        float4 h4 = *reinterpret_cast<const float4*>(h2 + (size_t)s * HD + l * 4);
        acc.x += p * h4.x; acc.y += p * h4.y; acc.z += p * h4.z; acc.w += p * h4.w;
    }
    sum += __shfl_xor(sum, 16); sum += __shfl_xor(sum, 32);
    acc.x += __shfl_xor(acc.x, 16); acc.x += __shfl_xor(acc.x, 32);
    acc.y += __shfl_xor(acc.y, 16); acc.y += __shfl_xor(acc.y, 32);
    acc.z += __shfl_xor(acc.z, 16); acc.z += __shfl_xor(acc.z, 32);
    acc.w += __shfl_xor(acc.w, 16); acc.w += __shfl_xor(acc.w, 32);

    if (sub == 0) {
        float inv = 1.0f / (sum + 1e-16f);
        float4 bb = *reinterpret_cast<const float4*>(b2 + l * 4);
        float4 r;
        r.x = acc.x * inv + bb.x; r.y = acc.y * inv + bb.y;
        r.z = acc.z * inv + bb.z; r.w = acc.w * inv + bb.w;
        *reinterpret_cast<float4*>(x2 + (size_t)v * HD + l * 4) = r;
    }
}

// ---------------------------------------------------------------- GRU gates (h0 = 0 => gh = bhh)
__global__ __launch_bounds__(256) void k_gru_gates(int n, const float* __restrict__ gi,
    const float* __restrict__ bih, const float* __restrict__ bhh, float* __restrict__ hout)
{
    int t = blockIdx.x * blockDim.x + threadIdx.x;
    if (t >= n * HD) return;
    int v = t >> 6, u = t & 63;
    const float* g = gi + (size_t)v * G3;
    float r  = sigm(g[u]        + bih[u]        + bhh[u]);
    float z  = sigm(g[64 + u]   + bih[64 + u]   + bhh[64 + u]);
    float nn = tanhf(g[128 + u] + bih[128 + u]  + r * bhh[128 + u]);
    hout[t] = (1.0f - z) * nn;
}

// ---------------------------------------------------------------- final FC (wave per node)
__global__ __launch_bounds__(256) void k_fc(int n, const float* __restrict__ h,
    const float* __restrict__ fcW, const float* __restrict__ fcb, float* __restrict__ out)
{
    int v = (blockIdx.x * blockDim.x + threadIdx.x) >> 6;
    int lane = threadIdx.x & 63;
    if (v >= n) return;
    float x = h[(size_t)v * HD + lane];
    float p0 = x * fcW[lane];
    float p1 = x * fcW[64 + lane];
    float p2 = x * fcW[128 + lane];
    #pragma unroll
    for (int off = 32; off > 0; off >>= 1) {
        p0 += __shfl_down(p0, off);
        p1 += __shfl_down(p1, off);
        p2 += __shfl_down(p2, off);
    }
    if (lane == 0) {
        out[(size_t)v * 3 + 0] = p0 + fcb[0];
        out[(size_t)v * 3 + 1] = p1 + fcb[1];
        out[(size_t)v * 3 + 2] = p2 + fcb[2];
    }
}

// ----------------------------------------------------------------
extern "C" void kernel_launch(void* const* d_in, const int* in_sizes, int n_in,
                              void* d_out, int out_size, void* d_ws, size_t ws_size,
                              hipStream_t stream)
{
    const float* x    = (const float*)d_in[0];
    const int*   eidx = (const int*)d_in[1];
    const float* W1   = (const float*)d_in[2];
    const float* aS1  = (const float*)d_in[3];
    const float* aD1  = (const float*)d_in[4];
    const float* b1   = (const float*)d_in[5];
    const float* W2   = (const float*)d_in[6];
    const float* aS2  = (const float*)d_in[7];
    const float* aD2  = (const float*)d_in[8];
    const float* b2   = (const float*)d_in[9];
    const float* Wih0 = (const float*)d_in[10];
    const float* bih0 = (const float*)d_in[12];
    const float* bhh0 = (const float*)d_in[13];
    const float* Wih1 = (const float*)d_in[14];
    const float* bih1 = (const float*)d_in[16];
    const float* bhh1 = (const float*)d_in[17];
    const float* fcW  = (const float*)d_in[18];
    const float* fcb  = (const float*)d_in[19];
    float* out = (float*)d_out;

    const int N = in_sizes[0] / N_FIN;
    const int E = in_sizes[1] / 2;
    const int* esrc = eidx;
    const int* edst = eidx + E;

    // ---- workspace layout (fp32 elements) ----
    float* f   = (float*)d_ws;
    float* h1  = f;                        // N*256   (aliased later by gi/hg)
    float* x1  = h1 + (size_t)N * C1;      // N*256
    float* g2  = x1 + (size_t)N * C1;      // N*64    GAT2 features
    float* x2  = g2 + (size_t)N * HD;      // N*64    GAT2 output (aliased later by hg2)
    float* as1 = x2 + (size_t)N * HD;      // N*4
    float* ad1 = as1 + (size_t)N * NH;     // N*4
    float* as2 = ad1 + (size_t)N * NH;     // N
    float* ad2 = as2 + (size_t)N;          // N
    int* ip     = (int*)(ad2 + N);
    int* deg    = ip;                      // N
    int* rowptr = deg + N;                 // N+1
    int* cursor = rowptr + N + 1;          // N
    int* incl   = cursor + N;              // N
    int* bsum   = incl + N;                // <=256
    int* col    = bsum + 256;              // E+N
    float* gi  = f;                        // N*192 (h1 dead by then)
    float* hg  = f + (size_t)N * G3;       // N*64  (tail of h1 region)
    float* hg2 = x2;                       // N*64  (x2 dead by then)

    const int nbN   = (N + 255) / 256;
    const int nbE   = (E + 255) / 256;
    const int nbEN  = (E + N + 255) / 256;
    const int nbW   = (N + 3) / 4;         // wave-per-node kernels, 4 waves/block
    const int nbNU  = (N * HD + 255) / 256;
    const int NB    = (N + 1023) / 1024;
    const int gM    = (N + 127) / 128;     // GEMM row-blocks

    // ---- CSR build ----
    k_deg_init<<<nbN, 256, 0, stream>>>(N, deg);
    k_hist<<<nbE, 256, 0, stream>>>(E, edst, deg);
    k_scan_block<<<NB, 1024, 0, stream>>>(N, deg, incl, bsum);
    k_scan_bsum<<<1, 64, 0, stream>>>(NB, bsum);
    k_rowptr<<<nbN, 256, 0, stream>>>(N, incl, bsum, rowptr);
    k_cursor<<<nbN, 256, 0, stream>>>(N, rowptr, cursor);
    k_fill<<<nbEN, 256, 0, stream>>>(E, N, esrc, edst, cursor, col);

    // ---- GAT layer 1: h1 = x @ W1 ----
    sgemm_big<128, 8, false><<<dim3(gM, C1 / 128), 256, 0, stream>>>(N, C1, N_FIN, x, N_FIN, W1, C1, h1, C1);
    k_att1<<<nbW, 256, 0, stream>>>(N, h1, aS1, aD1, as1, ad1);
    k_aggr1<<<nbW, 256, 0, stream>>>(N, rowptr, col, h1, as1, ad1, b1, x1);

    // ---- GAT layer 2: g2 = x1 @ W2 ----
    sgemm_big<64, 4, false><<<dim3(gM, HD / 64), 256, 0, stream>>>(N, HD, C1, x1, C1, W2, HD, g2, HD);
    k_att2<<<nbW, 256, 0, stream>>>(N, g2, aS2, aD2, as2, ad2);
    k_aggr2<<<nbW, 256, 0, stream>>>(N, rowptr, col, g2, as2, ad2, b2, x2);

    // ---- GRU layer 0: gi = x2 @ Wih0^T ; gates ----
    sgemm_big<64, 4, true><<<dim3(gM, G3 / 64), 256, 0, stream>>>(N, G3, HD, x2, HD, Wih0, HD, gi, G3);
    k_gru_gates<<<nbNU, 256, 0, stream>>>(N, gi, bih0, bhh0, hg);

    // ---- GRU layer 1 ----
    sgemm_big<64, 4, true><<<dim3(gM, G3 / 64), 256, 0, stream>>>(N, G3, HD, hg, HD, Wih1, HD, gi, G3);
    k_gru_gates<<<nbNU, 256, 0, stream>>>(N, gi, bih1, bhh1, hg2);

    // ---- FC ----
    k_fc<<<nbW, 256, 0, stream>>>(N, hg2, fcW, fcb, out);

    (void)n_in; (void)out_size; (void)ws_size;
}

// Round 7
// 708.622 us; speedup vs baseline: 1.5476x; 1.0814x over previous
//
#include <hip/hip_runtime.h>
#include <math.h>

#define N_FIN 128
#define C1    256   // HEADS*HID
#define NH    4
#define HD    64
#define G3    192   // 3*HID

static __device__ __forceinline__ float lrelu(float x) { return x >= 0.0f ? x : 0.2f * x; }
static __device__ __forceinline__ float sigm(float x)  { return 1.0f / (1.0f + __expf(-x)); }

// bf16 <-> f32 helpers (bf16 stored as raw ushort)
static __device__ __forceinline__ float bf2f(unsigned int u)
{
    union { unsigned int i; float f; } c; c.i = u << 16; return c.f;
}
static __device__ __forceinline__ unsigned short f2bf(float f)
{
    union { float f; unsigned int i; } c; c.f = f;
    unsigned int i = c.i + 0x7FFFu + ((c.i >> 16) & 1u);   // round-nearest-even
    return (unsigned short)(i >> 16);
}

// ---------------------------------------------------------------- CSR build
__global__ __launch_bounds__(256) void k_deg_init(int n, int* __restrict__ deg)
{
    int i = blockIdx.x * blockDim.x + threadIdx.x;
    if (i < n) deg[i] = 1;  // self-loop
}

__global__ __launch_bounds__(256) void k_hist(int E, const int* __restrict__ edst, int* __restrict__ deg)
{
    int e = blockIdx.x * blockDim.x + threadIdx.x;
    if (e < E) atomicAdd(&deg[edst[e]], 1);
}

__global__ __launch_bounds__(1024) void k_scan_block(int n, const int* __restrict__ deg,
                                                     int* __restrict__ incl, int* __restrict__ bsum)
{
    __shared__ int sh[1024];
    int t = threadIdx.x;
    int i = blockIdx.x * 1024 + t;
    sh[t] = (i < n) ? deg[i] : 0;
    __syncthreads();
    #pragma unroll
    for (int off = 1; off < 1024; off <<= 1) {
        int u = (t >= off) ? sh[t - off] : 0;
        __syncthreads();
        sh[t] += u;
        __syncthreads();
    }
    if (i < n) incl[i] = sh[t];
    if (t == 1023) bsum[blockIdx.x] = sh[1023];
}

__global__ void k_scan_bsum(int nb, int* __restrict__ bsum)
{
    if (threadIdx.x == 0 && blockIdx.x == 0) {
        int run = 0;
        for (int b = 0; b < nb; ++b) { int v = bsum[b]; bsum[b] = run; run += v; }
    }
}

__global__ __launch_bounds__(256) void k_rowptr(int n, const int* __restrict__ incl,
                                                const int* __restrict__ bsum, int* __restrict__ rowptr)
{
    int i = blockIdx.x * blockDim.x + threadIdx.x;
    if (i < n) rowptr[i + 1] = incl[i] + bsum[i >> 10];
    if (i == 0) rowptr[0] = 0;
}

__global__ __launch_bounds__(256) void k_cursor(int n, const int* __restrict__ rowptr, int* __restrict__ cursor)
{
    int i = blockIdx.x * blockDim.x + threadIdx.x;
    if (i < n) cursor[i] = rowptr[i];
}

__global__ __launch_bounds__(256) void k_fill(int E, int n, const int* __restrict__ esrc,
                                              const int* __restrict__ edst,
                                              int* __restrict__ cursor, int* __restrict__ col)
{
    int t = blockIdx.x * blockDim.x + threadIdx.x;
    if (t < E) {
        int p = atomicAdd(&cursor[edst[t]], 1);
        col[p] = esrc[t];
    } else if (t < E + n) {
        int v = t - E;
        int p = atomicAdd(&cursor[v], 1);
        col[p] = v;   // self-loop
    }
}

// ---------------------------------------------------------------- big-tile fp32 GEMM (optional bf16 output)
// BM=128, BK=16, 256 threads (16x16), micro-tile 8 x TN.
// TRANSB=false: C[M,N] = A[M,K] @ B[K,N];  TRANSB=true: C = A @ B[N,K]^T.
// OUTBF: store C as bf16 (raw ushort), same ldc in elements.
template<int BN, int TN, bool TRANSB, bool OUTBF>
__global__ __launch_bounds__(256) void sgemm_big(int M, int N, int K,
    const float* __restrict__ A, int lda, const float* __restrict__ B, int ldb,
    float* __restrict__ C, int ldc)
{
    __shared__ float As[16][132];      // transposed A-tile, padded (132 % 4 == 0 keeps f4 alignment)
    __shared__ float Bs[16][BN + 4];
    const int tid = threadIdx.x;
    const int tx = tid & 15, ty = tid >> 4;
    const int row0 = blockIdx.x * 128, col0 = blockIdx.y * BN;
    float acc[8][TN] = {};

    for (int k0 = 0; k0 < K; k0 += 16) {
        // A-tile: 128x16 = 512 float4, 2 per thread, stored transposed As[k][m]
        #pragma unroll
        for (int u = 0; u < 2; ++u) {
            int i = tid + u * 256;
            int r = i >> 2, kq = (i & 3) << 2;
            int arow = row0 + r; arow = arow < M ? arow : M - 1;
            float4 av = *reinterpret_cast<const float4*>(A + (size_t)arow * lda + k0 + kq);
            As[kq + 0][r] = av.x; As[kq + 1][r] = av.y; As[kq + 2][r] = av.z; As[kq + 3][r] = av.w;
        }
        // B-tile -> Bs[k][n]
        if constexpr (TRANSB) {
            // B[N,K]: BN rows x 4 float4 along K; BN=64 -> 256 f4 -> 1 per thread
            int nn = tid >> 2, kq = (tid & 3) << 2;
            float4 bv = *reinterpret_cast<const float4*>(B + (size_t)(col0 + nn) * ldb + k0 + kq);
            Bs[kq + 0][nn] = bv.x; Bs[kq + 1][nn] = bv.y; Bs[kq + 2][nn] = bv.z; Bs[kq + 3][nn] = bv.w;
        } else {
            #pragma unroll
            for (int u = 0; u < BN / 64; ++u) {
                int i = tid + u * 256;
                int kk = i / (BN / 4), n4 = (i % (BN / 4)) * 4;
                float4 bv = *reinterpret_cast<const float4*>(B + (size_t)(k0 + kk) * ldb + col0 + n4);
                *reinterpret_cast<float4*>(&Bs[kk][n4]) = bv;
            }
        }
        __syncthreads();
        #pragma unroll
        for (int k = 0; k < 16; ++k) {
            float a[8], b[TN];
            *reinterpret_cast<float4*>(&a[0]) = *reinterpret_cast<const float4*>(&As[k][ty * 8]);
            *reinterpret_cast<float4*>(&a[4]) = *reinterpret_cast<const float4*>(&As[k][ty * 8 + 4]);
            #pragma unroll
            for (int j = 0; j < TN; j += 4)
                *reinterpret_cast<float4*>(&b[j]) = *reinterpret_cast<const float4*>(&Bs[k][tx * TN + j]);
            #pragma unroll
            for (int i2 = 0; i2 < 8; ++i2)
                #pragma unroll
                for (int j = 0; j < TN; ++j)
                    acc[i2][j] += a[i2] * b[j];
        }
        __syncthreads();
    }
    #pragma unroll
    for (int i2 = 0; i2 < 8; ++i2) {
        int r = row0 + ty * 8 + i2;
        if (r < M) {
            if constexpr (OUTBF) {
                unsigned short* Cb = reinterpret_cast<unsigned short*>(C);
                #pragma unroll
                for (int j = 0; j < TN; j += 4) {
                    ushort4 o;
                    o.x = f2bf(acc[i2][j]);     o.y = f2bf(acc[i2][j + 1]);
                    o.z = f2bf(acc[i2][j + 2]); o.w = f2bf(acc[i2][j + 3]);
                    *reinterpret_cast<ushort4*>(Cb + (size_t)r * ldc + col0 + tx * TN + j) = o;
                }
            } else {
                #pragma unroll
                for (int j = 0; j < TN; j += 4) {
                    float4 o = make_float4(acc[i2][j], acc[i2][j + 1], acc[i2][j + 2], acc[i2][j + 3]);
                    *reinterpret_cast<float4*>(C + (size_t)r * ldc + col0 + tx * TN + j) = o;
                }
            }
        }
    }
}

// ---------------------------------------------------------------- attention coefficients (bf16 features)
__global__ __launch_bounds__(256) void k_att1(int n, const unsigned short* __restrict__ h1b,
    const float* __restrict__ att_src, const float* __restrict__ att_dst,
    float* __restrict__ a_src, float* __restrict__ a_dst)
{
    int v = (blockIdx.x * blockDim.x + threadIdx.x) >> 6;
    int lane = threadIdx.x & 63;
    if (v >= n) return;
    const unsigned short* hr = h1b + (size_t)v * C1;
    #pragma unroll
    for (int h = 0; h < NH; ++h) {
        float x = bf2f(hr[h * HD + lane]);
        float ps = x * att_src[h * HD + lane];
        float pd = x * att_dst[h * HD + lane];
        #pragma unroll
        for (int off = 32; off > 0; off >>= 1) {
            ps += __shfl_down(ps, off);
            pd += __shfl_down(pd, off);
        }
        if (lane == 0) { a_src[v * NH + h] = ps; a_dst[v * NH + h] = pd; }
    }
}

__global__ __launch_bounds__(256) void k_att2(int n, const unsigned short* __restrict__ h2b,
    const float* __restrict__ att_src, const float* __restrict__ att_dst,
    float* __restrict__ a_src, float* __restrict__ a_dst)
{
    int v = (blockIdx.x * blockDim.x + threadIdx.x) >> 6;
    int lane = threadIdx.x & 63;
    if (v >= n) return;
    float x = bf2f(h2b[(size_t)v * HD + lane]);
    float ps = x * att_src[lane];
    float pd = x * att_dst[lane];
    #pragma unroll
    for (int off = 32; off > 0; off >>= 1) {
        ps += __shfl_down(ps, off);
        pd += __shfl_down(pd, off);
    }
    if (lane == 0) { a_src[v] = ps; a_dst[v] = pd; }
}

// ---------------------------------------------------------------- GAT1 aggregation (bf16 gather)
// Single pass, no max subtraction (logits bounded; fminf(e,50) overflow guard).
// wave per dst node; 4x16-lane subgroups = 4 heads; lane handles 4 bf16 (uint2) of its head.
// Unrolled by 2 so two edges' gathers are in flight concurrently.
__global__ __launch_bounds__(256) void k_aggr1(int n, const int* __restrict__ rowptr,
    const int* __restrict__ col, const unsigned short* __restrict__ h1b,
    const float* __restrict__ a_src, const float* __restrict__ a_dst,
    const float* __restrict__ b1, float* __restrict__ x1)
{
    int v = (blockIdx.x * blockDim.x + threadIdx.x) >> 6;
    int lane = threadIdx.x & 63;
    if (v >= n) return;
    const int sub = lane >> 4;       // head
    const int l   = lane & 15;       // 4-elem slot within head
    int beg = rowptr[v], end = rowptr[v + 1];
    float ad = a_dst[(size_t)v * NH + sub];

    float sum = 0.0f;
    float4 acc = make_float4(0.f, 0.f, 0.f, 0.f);
    int i = beg;
    for (; i + 1 < end; i += 2) {
        int sA = col[i], sB = col[i + 1];
        float aA = a_src[(size_t)sA * NH + sub];
        float aB = a_src[(size_t)sB * NH + sub];
        uint2 uA = *reinterpret_cast<const uint2*>(h1b + (size_t)sA * C1 + sub * HD + l * 4);
        uint2 uB = *reinterpret_cast<const uint2*>(h1b + (size_t)sB * C1 + sub * HD + l * 4);
        float pA = __expf(fminf(lrelu(aA + ad), 50.f));
        float pB = __expf(fminf(lrelu(aB + ad), 50.f));
        sum += pA + pB;
        acc.x += pA * bf2f(uA.x & 0xffffu) + pB * bf2f(uB.x & 0xffffu);
        acc.y += pA * bf2f(uA.x >> 16)     + pB * bf2f(uB.x >> 16);
        acc.z += pA * bf2f(uA.y & 0xffffu) + pB * bf2f(uB.y & 0xffffu);
        acc.w += pA * bf2f(uA.y >> 16)     + pB * bf2f(uB.y >> 16);
    }
    if (i < end) {
        int s = col[i];
        float as = a_src[(size_t)s * NH + sub];
        uint2 u = *reinterpret_cast<const uint2*>(h1b + (size_t)s * C1 + sub * HD + l * 4);
        float p = __expf(fminf(lrelu(as + ad), 50.f));
        sum += p;
        acc.x += p * bf2f(u.x & 0xffffu);
        acc.y += p * bf2f(u.x >> 16);
        acc.z += p * bf2f(u.y & 0xffffu);
        acc.w += p * bf2f(u.y >> 16);
    }
    float inv = 1.0f / (sum + 1e-16f);
    float4 bb = *reinterpret_cast<const float4*>(b1 + sub * HD + l * 4);
    float4 r;
    r.x = acc.x * inv + bb.x; r.y = acc.y * inv + bb.y;
    r.z = acc.z * inv + bb.z; r.w = acc.w * inv + bb.w;
    r.x = r.x > 0.f ? r.x : 0.f; r.y = r.y > 0.f ? r.y : 0.f;
    r.z = r.z > 0.f ? r.z : 0.f; r.w = r.w > 0.f ? r.w : 0.f;
    *reinterpret_cast<float4*>(x1 + (size_t)v * C1 + sub * HD + l * 4) = r;
}

// ---------------------------------------------------------------- GAT2 aggregation (bf16 gather)
// Single pass, no max. wave per dst node; 4x16-lane subgroups stride the edge list;
// lane&15 handles 4 bf16 (uint2) of HD=64.
__global__ __launch_bounds__(256) void k_aggr2(int n, const int* __restrict__ rowptr,
    const int* __restrict__ col, const unsigned short* __restrict__ h2b,
    const float* __restrict__ a_src, const float* __restrict__ a_dst,
    const float* __restrict__ b2, float* __restrict__ x2)
{
    int v = (blockIdx.x * blockDim.x + threadIdx.x) >> 6;
    int lane = threadIdx.x & 63;
    if (v >= n) return;
    const int sub = lane >> 4;
    const int l   = lane & 15;
    int beg = rowptr[v], end = rowptr[v + 1];
    float ad = a_dst[v];

    float sum = 0.0f;
    float4 acc = make_float4(0.f, 0.f, 0.f, 0.f);
    for (int i = beg + sub; i < end; i += 4) {
        int s = col[i];
        float p = __expf(fminf(lrelu(a_src[s] + ad), 50.f));
        sum += p;
        uint2 u = *reinterpret_cast<const uint2*>(h2b + (size_t)s * HD + l * 4);
        acc.x += p * bf2f(u.x & 0xffffu);
        acc.y += p * bf2f(u.x >> 16);
        acc.z += p * bf2f(u.y & 0xffffu);
        acc.w += p * bf2f(u.y >> 16);
    }
    sum += __shfl_xor(sum, 16); sum += __shfl_xor(sum, 32);
    acc.x += __shfl_xor(acc.x, 16); acc.x += __shfl_xor(acc.x, 32);
    acc.y += __shfl_xor(acc.y, 16); acc.y += __shfl_xor(acc.y, 32);
    acc.z += __shfl_xor(acc.z, 16); acc.z += __shfl_xor(acc.z, 32);
    acc.w += __shfl_xor(acc.w, 16); acc.w += __shfl_xor(acc.w, 32);

    if (sub == 0) {
        float inv = 1.0f / (sum + 1e-16f);
        float4 bb = *reinterpret_cast<const float4*>(b2 + l * 4);
        float4 r;
        r.x = acc.x * inv + bb.x; r.y = acc.y * inv + bb.y;
        r.z = acc.z * inv + bb.z; r.w = acc.w * inv + bb.w;
        *reinterpret_cast<float4*>(x2 + (size_t)v * HD + l * 4) = r;
    }
}

// ---------------------------------------------------------------- GRU gates (h0 = 0 => gh = bhh)
__global__ __launch_bounds__(256) void k_gru_gates(int n, const float* __restrict__ gi,
    const float* __restrict__ bih, const float* __restrict__ bhh, float* __restrict__ hout)
{
    int t = blockIdx.x * blockDim.x + threadIdx.x;
    if (t >= n * HD) return;
    int v = t >> 6, u = t & 63;
    const float* g = gi + (size_t)v * G3;
    float r  = sigm(g[u]        + bih[u]        + bhh[u]);
    float z  = sigm(g[64 + u]   + bih[64 + u]   + bhh[64 + u]);
    float nn = tanhf(g[128 + u] + bih[128 + u]  + r * bhh[128 + u]);
    hout[t] = (1.0f - z) * nn;
}

// ---------------------------------------------------------------- final FC (wave per node)
__global__ __launch_bounds__(256) void k_fc(int n, const float* __restrict__ h,
    const float* __restrict__ fcW, const float* __restrict__ fcb, float* __restrict__ out)
{
    int v = (blockIdx.x * blockDim.x + threadIdx.x) >> 6;
    int lane = threadIdx.x & 63;
    if (v >= n) return;
    float x = h[(size_t)v * HD + lane];
    float p0 = x * fcW[lane];
    float p1 = x * fcW[64 + lane];
    float p2 = x * fcW[128 + lane];
    #pragma unroll
    for (int off = 32; off > 0; off >>= 1) {
        p0 += __shfl_down(p0, off);
        p1 += __shfl_down(p1, off);
        p2 += __shfl_down(p2, off);
    }
    if (lane == 0) {
        out[(size_t)v * 3 + 0] = p0 + fcb[0];
        out[(size_t)v * 3 + 1] = p1 + fcb[1];
        out[(size_t)v * 3 + 2] = p2 + fcb[2];
    }
}

// ----------------------------------------------------------------
extern "C" void kernel_launch(void* const* d_in, const int* in_sizes, int n_in,
                              void* d_out, int out_size, void* d_ws, size_t ws_size,
                              hipStream_t stream)
{
    const float* x    = (const float*)d_in[0];
    const int*   eidx = (const int*)d_in[1];
    const float* W1   = (const float*)d_in[2];
    const float* aS1  = (const float*)d_in[3];
    const float* aD1  = (const float*)d_in[4];
    const float* b1   = (const float*)d_in[5];
    const float* W2   = (const float*)d_in[6];
    const float* aS2  = (const float*)d_in[7];
    const float* aD2  = (const float*)d_in[8];
    const float* b2   = (const float*)d_in[9];
    const float* Wih0 = (const float*)d_in[10];
    const float* bih0 = (const float*)d_in[12];
    const float* bhh0 = (const float*)d_in[13];
    const float* Wih1 = (const float*)d_in[14];
    const float* bih1 = (const float*)d_in[16];
    const float* bhh1 = (const float*)d_in[17];
    const float* fcW  = (const float*)d_in[18];
    const float* fcb  = (const float*)d_in[19];
    float* out = (float*)d_out;

    const int N = in_sizes[0] / N_FIN;
    const int E = in_sizes[1] / 2;
    const int* esrc = eidx;
    const int* edst = eidx + E;

    // ---- workspace layout (fp32-element offsets; h1b/g2b are bf16 within their old slots) ----
    float* f   = (float*)d_ws;
    unsigned short* h1b = (unsigned short*)f;  // N*256 bf16 (first half of old h1 slot)
    float* x1  = f + (size_t)N * C1;           // N*256 fp32
    float* g2s = x1 + (size_t)N * C1;          // old g2 slot (N*64 floats)
    unsigned short* g2b = (unsigned short*)g2s; // N*64 bf16 (first half of slot)
    float* x2  = g2s + (size_t)N * HD;         // N*64 fp32 (aliased later by hg2)
    float* as1 = x2 + (size_t)N * HD;          // N*4
    float* ad1 = as1 + (size_t)N * NH;         // N*4
    float* as2 = ad1 + (size_t)N * NH;         // N
    float* ad2 = as2 + (size_t)N;              // N
    int* ip     = (int*)(ad2 + N);
    int* deg    = ip;                      // N
    int* rowptr = deg + N;                 // N+1
    int* cursor = rowptr + N + 1;          // N
    int* incl   = cursor + N;              // N
    int* bsum   = incl + N;                // <=256
    int* col    = bsum + 256;              // E+N
    float* gi  = f;                        // N*192 (h1b dead by then)
    float* hg  = f + (size_t)N * G3;       // N*64  (tail of old h1 region)
    float* hg2 = x2;                       // N*64  (x2 dead by then)

    const int nbN   = (N + 255) / 256;
    const int nbE   = (E + 255) / 256;
    const int nbEN  = (E + N + 255) / 256;
    const int nbW   = (N + 3) / 4;         // wave-per-node kernels, 4 waves/block
    const int nbNU  = (N * HD + 255) / 256;
    const int NB    = (N + 1023) / 1024;
    const int gM    = (N + 127) / 128;     // GEMM row-blocks

    // ---- CSR build ----
    k_deg_init<<<nbN, 256, 0, stream>>>(N, deg);
    k_hist<<<nbE, 256, 0, stream>>>(E, edst, deg);
    k_scan_block<<<NB, 1024, 0, stream>>>(N, deg, incl, bsum);
    k_scan_bsum<<<1, 64, 0, stream>>>(NB, bsum);
    k_rowptr<<<nbN, 256, 0, stream>>>(N, incl, bsum, rowptr);
    k_cursor<<<nbN, 256, 0, stream>>>(N, rowptr, cursor);
    k_fill<<<nbEN, 256, 0, stream>>>(E, N, esrc, edst, cursor, col);

    // ---- GAT layer 1: h1b = bf16(x @ W1) ----
    sgemm_big<128, 8, false, true><<<dim3(gM, C1 / 128), 256, 0, stream>>>(
        N, C1, N_FIN, x, N_FIN, W1, C1, (float*)h1b, C1);
    k_att1<<<nbW, 256, 0, stream>>>(N, h1b, aS1, aD1, as1, ad1);
    k_aggr1<<<nbW, 256, 0, stream>>>(N, rowptr, col, h1b, as1, ad1, b1, x1);

    // ---- GAT layer 2: g2b = bf16(x1 @ W2) ----
    sgemm_big<64, 4, false, true><<<dim3(gM, HD / 64), 256, 0, stream>>>(
        N, HD, C1, x1, C1, W2, HD, (float*)g2b, HD);
    k_att2<<<nbW, 256, 0, stream>>>(N, g2b, aS2, aD2, as2, ad2);
    k_aggr2<<<nbW, 256, 0, stream>>>(N, rowptr, col, g2b, as2, ad2, b2, x2);

    // ---- GRU layer 0: gi = x2 @ Wih0^T ; gates ----
    sgemm_big<64, 4, true, false><<<dim3(gM, G3 / 64), 256, 0, stream>>>(
        N, G3, HD, x2, HD, Wih0, HD, gi, G3);
    k_gru_gates<<<nbNU, 256, 0, stream>>>(N, gi, bih0, bhh0, hg);

    // ---- GRU layer 1 ----
    sgemm_big<64, 4, true, false><<<dim3(gM, G3 / 64), 256, 0, stream>>>(
        N, G3, HD, hg, HD, Wih1, HD, gi, G3);
    k_gru_gates<<<nbNU, 256, 0, stream>>>(N, gi, bih1, bhh1, hg2);

    // ---- FC ----
    k_fc<<<nbW, 256, 0, stream>>>(N, hg2, fcW, fcb, out);

    (void)n_in; (void)out_size; (void)ws_size;
}

// Round 8
// 553.310 us; speedup vs baseline: 1.9820x; 1.2807x over previous
//
#include <hip/hip_runtime.h>
#include <math.h>

#define N_FIN 128
#define C1    256   // HEADS*HID
#define NH    4
#define HD    64
#define G3    192   // 3*HID

typedef _Float16 f16x8 __attribute__((ext_vector_type(8)));
typedef float    f32x4 __attribute__((ext_vector_type(4)));

static __device__ __forceinline__ float lrelu(float x) { return x >= 0.0f ? x : 0.2f * x; }
static __device__ __forceinline__ float sigm(float x)  { return 1.0f / (1.0f + __expf(-x)); }

// bf16 <-> f32 helpers (bf16 stored as raw ushort)
static __device__ __forceinline__ float bf2f(unsigned int u)
{
    union { unsigned int i; float f; } c; c.i = u << 16; return c.f;
}
static __device__ __forceinline__ unsigned short f2bf(float f)
{
    union { float f; unsigned int i; } c; c.f = f;
    unsigned int i = c.i + 0x7FFFu + ((c.i >> 16) & 1u);   // round-nearest-even
    return (unsigned short)(i >> 16);
}

// ---------------------------------------------------------------- CSR build
__global__ __launch_bounds__(256) void k_deg_init(int n, int* __restrict__ deg)
{
    int i = blockIdx.x * blockDim.x + threadIdx.x;
    if (i < n) deg[i] = 1;  // self-loop
}

__global__ __launch_bounds__(256) void k_hist(int E, const int* __restrict__ edst, int* __restrict__ deg)
{
    int e = blockIdx.x * blockDim.x + threadIdx.x;
    if (e < E) atomicAdd(&deg[edst[e]], 1);
}

__global__ __launch_bounds__(1024) void k_scan_block(int n, const int* __restrict__ deg,
                                                     int* __restrict__ incl, int* __restrict__ bsum)
{
    __shared__ int sh[1024];
    int t = threadIdx.x;
    int i = blockIdx.x * 1024 + t;
    sh[t] = (i < n) ? deg[i] : 0;
    __syncthreads();
    #pragma unroll
    for (int off = 1; off < 1024; off <<= 1) {
        int u = (t >= off) ? sh[t - off] : 0;
        __syncthreads();
        sh[t] += u;
        __syncthreads();
    }
    if (i < n) incl[i] = sh[t];
    if (t == 1023) bsum[blockIdx.x] = sh[1023];
}

__global__ void k_scan_bsum(int nb, int* __restrict__ bsum)
{
    if (threadIdx.x == 0 && blockIdx.x == 0) {
        int run = 0;
        for (int b = 0; b < nb; ++b) { int v = bsum[b]; bsum[b] = run; run += v; }
    }
}

__global__ __launch_bounds__(256) void k_rowptr(int n, const int* __restrict__ incl,
                                                const int* __restrict__ bsum, int* __restrict__ rowptr)
{
    int i = blockIdx.x * blockDim.x + threadIdx.x;
    if (i < n) rowptr[i + 1] = incl[i] + bsum[i >> 10];
    if (i == 0) rowptr[0] = 0;
}

__global__ __launch_bounds__(256) void k_cursor(int n, const int* __restrict__ rowptr, int* __restrict__ cursor)
{
    int i = blockIdx.x * blockDim.x + threadIdx.x;
    if (i < n) cursor[i] = rowptr[i];
}

__global__ __launch_bounds__(256) void k_fill(int E, int n, const int* __restrict__ esrc,
                                              const int* __restrict__ edst,
                                              int* __restrict__ cursor, int* __restrict__ col)
{
    int t = blockIdx.x * blockDim.x + threadIdx.x;
    if (t < E) {
        int p = atomicAdd(&cursor[edst[t]], 1);
        col[p] = esrc[t];
    } else if (t < E + n) {
        int v = t - E;
        int p = atomicAdd(&cursor[v], 1);
        col[p] = v;   // self-loop
    }
}

// ---------------------------------------------------------------- fp16 MFMA GEMM
// C[M,N] = A[M,K] @ B[K,N], fp32 accumulate, bf16 (ushort) output.
// BM=128, BK=32, 256 threads = 4 waves; wave w owns rows [w*32, w*32+32).
// v_mfma_f32_16x16x32_f16 fragments: A row=l&15, k=(l>>4)*8+j; B col=l&15, same k;
// C/D col=l&15, row=(l>>4)*4+reg (verified layout).
// AHALF: A is _Float16 (else fp32, converted during staging). B always fp32, L2-hot weights.
template<int BN, bool AHALF>
__global__ __launch_bounds__(256) void gemm_mfma(int M, int K,
    const void* __restrict__ Ap, int lda, const float* __restrict__ B, int ldb,
    unsigned short* __restrict__ C, int ldc)
{
    __shared__ _Float16 Al[128][40];   // pad to 40 halves: 80 B row stride, 16B-aligned, bank-spread
    __shared__ _Float16 Bt[BN][40];    // B stored transposed: Bt[n][k]
    const int tid = threadIdx.x;
    const int wid = tid >> 6, l = tid & 63;
    const int l15 = l & 15, lk = (l >> 4) * 8;
    const int row0 = blockIdx.x * 128, col0 = blockIdx.y * BN;

    f32x4 acc[2][BN / 16];
    #pragma unroll
    for (int rf = 0; rf < 2; ++rf)
        #pragma unroll
        for (int cf = 0; cf < BN / 16; ++cf)
            acc[rf][cf] = (f32x4){0.f, 0.f, 0.f, 0.f};

    for (int k0 = 0; k0 < K; k0 += 32) {
        // ---- stage A (128 x 32) ----
        if (AHALF) {
            const _Float16* A = (const _Float16*)Ap;
            #pragma unroll
            for (int u = 0; u < 2; ++u) {
                int i = tid + u * 256;
                int r = i >> 2, kq = (i & 3) * 8;
                int ar = row0 + r; ar = ar < M ? ar : M - 1;
                *(f16x8*)&Al[r][kq] = *(const f16x8*)(A + (size_t)ar * lda + k0 + kq);
            }
        } else {
            const float* A = (const float*)Ap;
            #pragma unroll
            for (int u = 0; u < 4; ++u) {
                int i = tid + u * 256;
                int r = i >> 3, kq = (i & 7) * 4;
                int ar = row0 + r; ar = ar < M ? ar : M - 1;
                float4 v = *(const float4*)(A + (size_t)ar * lda + k0 + kq);
                Al[r][kq + 0] = (_Float16)v.x; Al[r][kq + 1] = (_Float16)v.y;
                Al[r][kq + 2] = (_Float16)v.z; Al[r][kq + 3] = (_Float16)v.w;
            }
        }
        // ---- stage B rows k0..k0+31 -> Bt[n][k] (weights tiny, L2-hot) ----
        {
            constexpr int GK  = 256 / BN;   // thread groups along k
            constexpr int KPG = 32 / GK;    // k per group
            int n = tid % BN, kh = tid / BN;
            #pragma unroll
            for (int g = 0; g < KPG / 8; ++g) {
                f16x8 t;
                #pragma unroll
                for (int kk = 0; kk < 8; ++kk)
                    t[kk] = (_Float16)B[(size_t)(k0 + kh * KPG + g * 8 + kk) * ldb + col0 + n];
                *(f16x8*)&Bt[n][kh * KPG + g * 8] = t;
            }
        }
        __syncthreads();
        f16x8 a0 = *(const f16x8*)&Al[wid * 32 + l15][lk];
        f16x8 a1 = *(const f16x8*)&Al[wid * 32 + 16 + l15][lk];
        #pragma unroll
        for (int cf = 0; cf < BN / 16; ++cf) {
            f16x8 b = *(const f16x8*)&Bt[cf * 16 + l15][lk];
            acc[0][cf] = __builtin_amdgcn_mfma_f32_16x16x32_f16(a0, b, acc[0][cf], 0, 0, 0);
            acc[1][cf] = __builtin_amdgcn_mfma_f32_16x16x32_f16(a1, b, acc[1][cf], 0, 0, 0);
        }
        __syncthreads();
    }
    // ---- epilogue: bf16 store ----
    #pragma unroll
    for (int rf = 0; rf < 2; ++rf)
        #pragma unroll
        for (int i = 0; i < 4; ++i) {
            int r = row0 + wid * 32 + rf * 16 + (l >> 4) * 4 + i;
            if (r < M) {
                #pragma unroll
                for (int cf = 0; cf < BN / 16; ++cf)
                    C[(size_t)r * ldc + col0 + cf * 16 + l15] = f2bf(acc[rf][cf][i]);
            }
        }
}

// ---------------------------------------------------------------- fused GRU layer (MFMA + gates)
// h = GRUCell(x, h0=0): gi = x @ Wih^T; r=sig(gi_r+bih_r+bhh_r); z=sig(...);
// n=tanh(gi_n+bih_n+r*bhh_n); h=(1-z)*n.  BN=192 covers all 3 gates; r/z/n of unit u
// land in the SAME lane (frags cf, cf+4, cf+8) -> gates computed in-register, gi never stored.
__global__ __launch_bounds__(256) void k_gru_mfma(int M,
    const _Float16* __restrict__ A,          // M x 64 (fp16)
    const float* __restrict__ Wih,           // 192 x 64 (row-major: already Bt orientation)
    const float* __restrict__ bih, const float* __restrict__ bhh,
    _Float16* __restrict__ hout)             // M x 64 (fp16)
{
    __shared__ _Float16 Al[128][72];   // 64+8 pad: 144 B stride
    __shared__ _Float16 Bt[192][72];
    const int tid = threadIdx.x, wid = tid >> 6, l = tid & 63;
    const int l15 = l & 15, lk = (l >> 4) * 8;
    const int row0 = blockIdx.x * 128;

    f32x4 acc[2][12];
    #pragma unroll
    for (int rf = 0; rf < 2; ++rf)
        #pragma unroll
        for (int cf = 0; cf < 12; ++cf)
            acc[rf][cf] = (f32x4){0.f, 0.f, 0.f, 0.f};

    // stage A: 128 x 64 halves
    #pragma unroll
    for (int u = 0; u < 4; ++u) {
        int i = tid + u * 256;
        int r = i >> 3, kq = (i & 7) * 8;
        int ar = row0 + r; ar = ar < M ? ar : M - 1;
        *(f16x8*)&Al[r][kq] = *(const f16x8*)(A + (size_t)ar * 64 + kq);
    }
    // stage Wih (192 x 64 fp32, L2-hot)
    if (tid < 192) {
        #pragma unroll
        for (int kq = 0; kq < 64; kq += 4) {
            float4 v = *(const float4*)(Wih + (size_t)tid * 64 + kq);
            Bt[tid][kq + 0] = (_Float16)v.x; Bt[tid][kq + 1] = (_Float16)v.y;
            Bt[tid][kq + 2] = (_Float16)v.z; Bt[tid][kq + 3] = (_Float16)v.w;
        }
    }
    __syncthreads();
    #pragma unroll
    for (int ks = 0; ks < 2; ++ks) {
        f16x8 a0 = *(const f16x8*)&Al[wid * 32 + l15][ks * 32 + lk];
        f16x8 a1 = *(const f16x8*)&Al[wid * 32 + 16 + l15][ks * 32 + lk];
        #pragma unroll
        for (int cf = 0; cf < 12; ++cf) {
            f16x8 b = *(const f16x8*)&Bt[cf * 16 + l15][ks * 32 + lk];
            acc[0][cf] = __builtin_amdgcn_mfma_f32_16x16x32_f16(a0, b, acc[0][cf], 0, 0, 0);
            acc[1][cf] = __builtin_amdgcn_mfma_f32_16x16x32_f16(a1, b, acc[1][cf], 0, 0, 0);
        }
    }
    // gates epilogue (h0=0 => gh = bhh)
    #pragma unroll
    for (int rf = 0; rf < 2; ++rf)
        #pragma unroll
        for (int i = 0; i < 4; ++i) {
            int r = row0 + wid * 32 + rf * 16 + (l >> 4) * 4 + i;
            if (r < M) {
                #pragma unroll
                for (int cf = 0; cf < 4; ++cf) {
                    int u = cf * 16 + l15;
                    float gr = acc[rf][cf][i]     + bih[u]       + bhh[u];
                    float gz = acc[rf][cf + 4][i] + bih[64 + u]  + bhh[64 + u];
                    float rr = sigm(gr), zz = sigm(gz);
                    float nn = tanhf(acc[rf][cf + 8][i] + bih[128 + u] + rr * bhh[128 + u]);
                    hout[(size_t)r * 64 + u] = (_Float16)((1.0f - zz) * nn);
                }
            }
        }
}

// ---------------------------------------------------------------- attention coefficients (bf16 features)
__global__ __launch_bounds__(256) void k_att1(int n, const unsigned short* __restrict__ h1b,
    const float* __restrict__ att_src, const float* __restrict__ att_dst,
    float* __restrict__ a_src, float* __restrict__ a_dst)
{
    int v = (blockIdx.x * blockDim.x + threadIdx.x) >> 6;
    int lane = threadIdx.x & 63;
    if (v >= n) return;
    const unsigned short* hr = h1b + (size_t)v * C1;
    #pragma unroll
    for (int h = 0; h < NH; ++h) {
        float x = bf2f(hr[h * HD + lane]);
        float ps = x * att_src[h * HD + lane];
        float pd = x * att_dst[h * HD + lane];
        #pragma unroll
        for (int off = 32; off > 0; off >>= 1) {
            ps += __shfl_down(ps, off);
            pd += __shfl_down(pd, off);
        }
        if (lane == 0) { a_src[v * NH + h] = ps; a_dst[v * NH + h] = pd; }
    }
}

__global__ __launch_bounds__(256) void k_att2(int n, const unsigned short* __restrict__ h2b,
    const float* __restrict__ att_src, const float* __restrict__ att_dst,
    float* __restrict__ a_src, float* __restrict__ a_dst)
{
    int v = (blockIdx.x * blockDim.x + threadIdx.x) >> 6;
    int lane = threadIdx.x & 63;
    if (v >= n) return;
    float x = bf2f(h2b[(size_t)v * HD + lane]);
    float ps = x * att_src[lane];
    float pd = x * att_dst[lane];
    #pragma unroll
    for (int off = 32; off > 0; off >>= 1) {
        ps += __shfl_down(ps, off);
        pd += __shfl_down(pd, off);
    }
    if (lane == 0) { a_src[v] = ps; a_dst[v] = pd; }
}

// ---------------------------------------------------------------- GAT1 aggregation (bf16 gather, fp16 out)
__global__ __launch_bounds__(256) void k_aggr1(int n, const int* __restrict__ rowptr,
    const int* __restrict__ col, const unsigned short* __restrict__ h1b,
    const float* __restrict__ a_src, const float* __restrict__ a_dst,
    const float* __restrict__ b1, _Float16* __restrict__ x1h)
{
    int v = (blockIdx.x * blockDim.x + threadIdx.x) >> 6;
    int lane = threadIdx.x & 63;
    if (v >= n) return;
    const int sub = lane >> 4;       // head
    const int l   = lane & 15;       // 4-elem slot within head
    int beg = rowptr[v], end = rowptr[v + 1];
    float ad = a_dst[(size_t)v * NH + sub];

    float sum = 0.0f;
    float4 acc = make_float4(0.f, 0.f, 0.f, 0.f);
    int i = beg;
    for (; i + 1 < end; i += 2) {
        int sA = col[i], sB = col[i + 1];
        float aA = a_src[(size_t)sA * NH + sub];
        float aB = a_src[(size_t)sB * NH + sub];
        uint2 uA = *reinterpret_cast<const uint2*>(h1b + (size_t)sA * C1 + sub * HD + l * 4);
        uint2 uB = *reinterpret_cast<const uint2*>(h1b + (size_t)sB * C1 + sub * HD + l * 4);
        float pA = __expf(fminf(lrelu(aA + ad), 50.f));
        float pB = __expf(fminf(lrelu(aB + ad), 50.f));
        sum += pA + pB;
        acc.x += pA * bf2f(uA.x & 0xffffu) + pB * bf2f(uB.x & 0xffffu);
        acc.y += pA * bf2f(uA.x >> 16)     + pB * bf2f(uB.x >> 16);
        acc.z += pA * bf2f(uA.y & 0xffffu) + pB * bf2f(uB.y & 0xffffu);
        acc.w += pA * bf2f(uA.y >> 16)     + pB * bf2f(uB.y >> 16);
    }
    if (i < end) {
        int s = col[i];
        float as = a_src[(size_t)s * NH + sub];
        uint2 u = *reinterpret_cast<const uint2*>(h1b + (size_t)s * C1 + sub * HD + l * 4);
        float p = __expf(fminf(lrelu(as + ad), 50.f));
        sum += p;
        acc.x += p * bf2f(u.x & 0xffffu);
        acc.y += p * bf2f(u.x >> 16);
        acc.z += p * bf2f(u.y & 0xffffu);
        acc.w += p * bf2f(u.y >> 16);
    }
    float inv = 1.0f / (sum + 1e-16f);
    float4 bb = *reinterpret_cast<const float4*>(b1 + sub * HD + l * 4);
    float rx = acc.x * inv + bb.x, ry = acc.y * inv + bb.y;
    float rz = acc.z * inv + bb.z, rw = acc.w * inv + bb.w;
    _Float16 o[4];
    o[0] = (_Float16)(rx > 0.f ? rx : 0.f);
    o[1] = (_Float16)(ry > 0.f ? ry : 0.f);
    o[2] = (_Float16)(rz > 0.f ? rz : 0.f);
    o[3] = (_Float16)(rw > 0.f ? rw : 0.f);
    *reinterpret_cast<uint2*>(x1h + (size_t)v * C1 + sub * HD + l * 4) = *reinterpret_cast<uint2*>(o);
}

// ---------------------------------------------------------------- GAT2 aggregation (bf16 gather, fp16 out)
__global__ __launch_bounds__(256) void k_aggr2(int n, const int* __restrict__ rowptr,
    const int* __restrict__ col, const unsigned short* __restrict__ h2b,
    const float* __restrict__ a_src, const float* __restrict__ a_dst,
    const float* __restrict__ b2, _Float16* __restrict__ x2h)
{
    int v = (blockIdx.x * blockDim.x + threadIdx.x) >> 6;
    int lane = threadIdx.x & 63;
    if (v >= n) return;
    const int sub = lane >> 4;
    const int l   = lane & 15;
    int beg = rowptr[v], end = rowptr[v + 1];
    float ad = a_dst[v];

    float sum = 0.0f;
    float4 acc = make_float4(0.f, 0.f, 0.f, 0.f);
    for (int i = beg + sub; i < end; i += 4) {
        int s = col[i];
        float p = __expf(fminf(lrelu(a_src[s] + ad), 50.f));
        sum += p;
        uint2 u = *reinterpret_cast<const uint2*>(h2b + (size_t)s * HD + l * 4);
        acc.x += p * bf2f(u.x & 0xffffu);
        acc.y += p * bf2f(u.x >> 16);
        acc.z += p * bf2f(u.y & 0xffffu);
        acc.w += p * bf2f(u.y >> 16);
    }
    sum += __shfl_xor(sum, 16); sum += __shfl_xor(sum, 32);
    acc.x += __shfl_xor(acc.x, 16); acc.x += __shfl_xor(acc.x, 32);
    acc.y += __shfl_xor(acc.y, 16); acc.y += __shfl_xor(acc.y, 32);
    acc.z += __shfl_xor(acc.z, 16); acc.z += __shfl_xor(acc.z, 32);
    acc.w += __shfl_xor(acc.w, 16); acc.w += __shfl_xor(acc.w, 32);

    if (sub == 0) {
        float inv = 1.0f / (sum + 1e-16f);
        float4 bb = *reinterpret_cast<const float4*>(b2 + l * 4);
        _Float16 o[4];
        o[0] = (_Float16)(acc.x * inv + bb.x);
        o[1] = (_Float16)(acc.y * inv + bb.y);
        o[2] = (_Float16)(acc.z * inv + bb.z);
        o[3] = (_Float16)(acc.w * inv + bb.w);
        *reinterpret_cast<uint2*>(x2h + (size_t)v * HD + l * 4) = *reinterpret_cast<uint2*>(o);
    }
}

// ---------------------------------------------------------------- final FC (wave per node, fp16 in)
__global__ __launch_bounds__(256) void k_fc(int n, const _Float16* __restrict__ h,
    const float* __restrict__ fcW, const float* __restrict__ fcb, float* __restrict__ out)
{
    int v = (blockIdx.x * blockDim.x + threadIdx.x) >> 6;
    int lane = threadIdx.x & 63;
    if (v >= n) return;
    float x = (float)h[(size_t)v * HD + lane];
    float p0 = x * fcW[lane];
    float p1 = x * fcW[64 + lane];
    float p2 = x * fcW[128 + lane];
    #pragma unroll
    for (int off = 32; off > 0; off >>= 1) {
        p0 += __shfl_down(p0, off);
        p1 += __shfl_down(p1, off);
        p2 += __shfl_down(p2, off);
    }
    if (lane == 0) {
        out[(size_t)v * 3 + 0] = p0 + fcb[0];
        out[(size_t)v * 3 + 1] = p1 + fcb[1];
        out[(size_t)v * 3 + 2] = p2 + fcb[2];
    }
}

// ----------------------------------------------------------------
extern "C" void kernel_launch(void* const* d_in, const int* in_sizes, int n_in,
                              void* d_out, int out_size, void* d_ws, size_t ws_size,
                              hipStream_t stream)
{
    const float* x    = (const float*)d_in[0];
    const int*   eidx = (const int*)d_in[1];
    const float* W1   = (const float*)d_in[2];
    const float* aS1  = (const float*)d_in[3];
    const float* aD1  = (const float*)d_in[4];
    const float* b1   = (const float*)d_in[5];
    const float* W2   = (const float*)d_in[6];
    const float* aS2  = (const float*)d_in[7];
    const float* aD2  = (const float*)d_in[8];
    const float* b2   = (const float*)d_in[9];
    const float* Wih0 = (const float*)d_in[10];
    const float* bih0 = (const float*)d_in[12];
    const float* bhh0 = (const float*)d_in[13];
    const float* Wih1 = (const float*)d_in[14];
    const float* bih1 = (const float*)d_in[16];
    const float* bhh1 = (const float*)d_in[17];
    const float* fcW  = (const float*)d_in[18];
    const float* fcb  = (const float*)d_in[19];
    float* out = (float*)d_out;

    const int N = in_sizes[0] / N_FIN;
    const int E = in_sizes[1] / 2;
    const int* esrc = eidx;
    const int* edst = eidx + E;

    // ---- workspace layout (float-element offsets; sub-slots reinterpreted) ----
    float* f = (float*)d_ws;
    unsigned short* h1b = (unsigned short*)f;              // N*256 bf16 (slot 0)
    _Float16* hg  = (_Float16*)f;                          // N*64 fp16 (slot 0 reuse; h1b dead)
    _Float16* x1h = (_Float16*)(f + (size_t)N * C1);       // N*256 fp16
    float* g2s = f + 2 * (size_t)N * C1;                   // slot (N*64 floats)
    unsigned short* g2b = (unsigned short*)g2s;            // N*64 bf16
    float* x2s = g2s + (size_t)N * HD;                     // slot (N*64 floats)
    _Float16* x2h = (_Float16*)x2s;                        // N*64 fp16
    _Float16* hg2 = (_Float16*)x2s;                        // N*64 fp16 (x2h dead by GRU2)
    float* as1 = x2s + (size_t)N * HD;                     // N*4
    float* ad1 = as1 + (size_t)N * NH;                     // N*4
    float* as2 = ad1 + (size_t)N * NH;                     // N
    float* ad2 = as2 + (size_t)N;                          // N
    int* ip     = (int*)(ad2 + N);
    int* deg    = ip;                      // N
    int* rowptr = deg + N;                 // N+1
    int* cursor = rowptr + N + 1;          // N
    int* incl   = cursor + N;              // N
    int* bsum   = incl + N;                // <=256
    int* col    = bsum + 256;              // E+N

    const int nbN   = (N + 255) / 256;
    const int nbE   = (E + 255) / 256;
    const int nbEN  = (E + N + 255) / 256;
    const int nbW   = (N + 3) / 4;         // wave-per-node kernels, 4 waves/block
    const int NB    = (N + 1023) / 1024;
    const int gM    = (N + 127) / 128;     // MFMA row-blocks

    // ---- CSR build ----
    k_deg_init<<<nbN, 256, 0, stream>>>(N, deg);
    k_hist<<<nbE, 256, 0, stream>>>(E, edst, deg);
    k_scan_block<<<NB, 1024, 0, stream>>>(N, deg, incl, bsum);
    k_scan_bsum<<<1, 64, 0, stream>>>(NB, bsum);
    k_rowptr<<<nbN, 256, 0, stream>>>(N, incl, bsum, rowptr);
    k_cursor<<<nbN, 256, 0, stream>>>(N, rowptr, cursor);
    k_fill<<<nbEN, 256, 0, stream>>>(E, N, esrc, edst, cursor, col);

    // ---- GAT layer 1: h1b = bf16(x @ W1), MFMA fp16 ----
    gemm_mfma<128, false><<<dim3(gM, 2), 256, 0, stream>>>(N, N_FIN, x, N_FIN, W1, C1, h1b, C1);
    k_att1<<<nbW, 256, 0, stream>>>(N, h1b, aS1, aD1, as1, ad1);
    k_aggr1<<<nbW, 256, 0, stream>>>(N, rowptr, col, h1b, as1, ad1, b1, x1h);

    // ---- GAT layer 2: g2b = bf16(x1 @ W2), MFMA fp16 ----
    gemm_mfma<64, true><<<dim3(gM, 1), 256, 0, stream>>>(N, C1, x1h, C1, W2, HD, g2b, HD);
    k_att2<<<nbW, 256, 0, stream>>>(N, g2b, aS2, aD2, as2, ad2);
    k_aggr2<<<nbW, 256, 0, stream>>>(N, rowptr, col, g2b, as2, ad2, b2, x2h);

    // ---- GRU layers: fused MFMA + gates (gi never materialized) ----
    k_gru_mfma<<<gM, 256, 0, stream>>>(N, x2h, Wih0, bih0, bhh0, hg);
    k_gru_mfma<<<gM, 256, 0, stream>>>(N, hg,  Wih1, bih1, bhh1, hg2);

    // ---- FC ----
    k_fc<<<nbW, 256, 0, stream>>>(N, hg2, fcW, fcb, out);

    (void)n_in; (void)out_size; (void)ws_size;
}

// Round 10
// 492.964 us; speedup vs baseline: 2.2246x; 1.1224x over previous
//
#include <hip/hip_runtime.h>
#include <math.h>

#define N_FIN 128
#define C1    256   // HEADS*HID
#define NH    4
#define HD    64

typedef _Float16 f16x8 __attribute__((ext_vector_type(8)));
typedef float    f32x4 __attribute__((ext_vector_type(4)));

static __device__ __forceinline__ float lrelu(float x) { return x >= 0.0f ? x : 0.2f * x; }
static __device__ __forceinline__ float sigm(float x)  { return 1.0f / (1.0f + __expf(-x)); }

static __device__ __forceinline__ float bf2f(unsigned int u)
{
    union { unsigned int i; float f; } c; c.i = u << 16; return c.f;
}
static __device__ __forceinline__ unsigned short f2bf(float f)
{
    union { float f; unsigned int i; } c; c.f = f;
    unsigned int i = c.i + 0x7FFFu + ((c.i >> 16) & 1u);   // round-nearest-even
    return (unsigned short)(i >> 16);
}

// ---------------------------------------------------------------- CSR build
// deg[] zeroed via hipMemsetAsync; self-loops accounted analytically (+i+1 in rowptr).
__global__ __launch_bounds__(256) void k_hist(int E, const int* __restrict__ edst, int* __restrict__ deg)
{
    int e = blockIdx.x * blockDim.x + threadIdx.x;
    if (e < E) atomicAdd(&deg[edst[e]], 1);
}

__global__ __launch_bounds__(1024) void k_scan_block(int n, const int* __restrict__ deg,
                                                     int* __restrict__ incl, int* __restrict__ bsum)
{
    __shared__ int sh[1024];
    int t = threadIdx.x;
    int i = blockIdx.x * 1024 + t;
    sh[t] = (i < n) ? deg[i] : 0;
    __syncthreads();
    #pragma unroll
    for (int off = 1; off < 1024; off <<= 1) {
        int u = (t >= off) ? sh[t - off] : 0;
        __syncthreads();
        sh[t] += u;
        __syncthreads();
    }
    if (i < n) incl[i] = sh[t];
    if (t == 1023) bsum[blockIdx.x] = sh[1023];
}

__global__ void k_scan_bsum(int nb, int* __restrict__ bsum)
{
    if (threadIdx.x == 0 && blockIdx.x == 0) {
        int run = 0;
        for (int b = 0; b < nb; ++b) { int v = bsum[b]; bsum[b] = run; run += v; }
    }
}

// rowptr[i+1] = inclusive-edge-scan(i) + (i+1 self-loops); cursor folded in.
__global__ __launch_bounds__(256) void k_rowptr(int n, const int* __restrict__ incl,
                                                const int* __restrict__ bsum,
                                                int* __restrict__ rowptr, int* __restrict__ cursor)
{
    int i = blockIdx.x * blockDim.x + threadIdx.x;
    if (i < n) {
        int v = incl[i] + bsum[i >> 10] + (i + 1);
        rowptr[i + 1] = v;
        if (i + 1 < n) cursor[i + 1] = v;
        if (i == 0) { rowptr[0] = 0; cursor[0] = 0; }
    }
}

__global__ __launch_bounds__(256) void k_fill(int E, int n, const int* __restrict__ esrc,
                                              const int* __restrict__ edst,
                                              int* __restrict__ cursor, int* __restrict__ col)
{
    int t = blockIdx.x * blockDim.x + threadIdx.x;
    if (t < E) {
        int p = atomicAdd(&cursor[edst[t]], 1);
        col[p] = esrc[t];
    } else if (t < E + n) {
        int v = t - E;
        int p = atomicAdd(&cursor[v], 1);
        col[p] = v;   // self-loop
    }
}

// ---------------------------------------------------------------- fp16 MFMA GEMM + fused attention coeffs
// C[M,BN] = A[M,K] @ B[K,BN] (fp32 acc, bf16 out). BM=128, BK=32, 4 waves.
// Per-row a_src/a_dst = h . att (64-col heads, 4 cf per head) computed from
// fp32 acc via 16-lane shfl_xor reduction (C/D layout: col=l&15, row=(l>>4)*4+reg).
template<int BN, int NHEADS, bool AHALF>
__global__ __launch_bounds__(256) void gemm_mfma(int M, int K,
    const void* __restrict__ Ap, int lda, const float* __restrict__ B, int ldb,
    unsigned short* __restrict__ C, int ldc,
    const float* __restrict__ att_src, const float* __restrict__ att_dst,
    float* __restrict__ a_src, float* __restrict__ a_dst)
{
    __shared__ _Float16 Al[128][40];   // 80 B row stride (16B-aligned, bank-spread)
    __shared__ _Float16 Bt[BN][40];
    const int tid = threadIdx.x;
    const int wid = tid >> 6, l = tid & 63;
    const int l15 = l & 15, lk = (l >> 4) * 8;
    const int row0 = blockIdx.x * 128;

    f32x4 acc[2][BN / 16];
    #pragma unroll
    for (int rf = 0; rf < 2; ++rf)
        #pragma unroll
        for (int cf = 0; cf < BN / 16; ++cf)
            acc[rf][cf] = (f32x4){0.f, 0.f, 0.f, 0.f};

    for (int k0 = 0; k0 < K; k0 += 32) {
        if (AHALF) {
            const _Float16* A = (const _Float16*)Ap;
            #pragma unroll
            for (int u = 0; u < 2; ++u) {
                int i = tid + u * 256;
                int r = i >> 2, kq = (i & 3) * 8;
                int ar = row0 + r; ar = ar < M ? ar : M - 1;
                *(f16x8*)&Al[r][kq] = *(const f16x8*)(A + (size_t)ar * lda + k0 + kq);
            }
        } else {
            const float* A = (const float*)Ap;
            #pragma unroll
            for (int u = 0; u < 4; ++u) {
                int i = tid + u * 256;
                int r = i >> 3, kq = (i & 7) * 4;
                int ar = row0 + r; ar = ar < M ? ar : M - 1;
                float4 v = *(const float4*)(A + (size_t)ar * lda + k0 + kq);
                Al[r][kq + 0] = (_Float16)v.x; Al[r][kq + 1] = (_Float16)v.y;
                Al[r][kq + 2] = (_Float16)v.z; Al[r][kq + 3] = (_Float16)v.w;
            }
        }
        {   // stage B -> Bt[n][k] (weights L2-hot)
            constexpr int GK  = 256 / BN;
            constexpr int KPG = 32 / GK;
            int n = tid % BN, kh = tid / BN;
            #pragma unroll
            for (int g = 0; g < KPG / 8; ++g) {
                f16x8 t;
                #pragma unroll
                for (int kk = 0; kk < 8; ++kk)
                    t[kk] = (_Float16)B[(size_t)(k0 + kh * KPG + g * 8 + kk) * ldb + n];
                *(f16x8*)&Bt[n][kh * KPG + g * 8] = t;
            }
        }
        __syncthreads();
        f16x8 a0 = *(const f16x8*)&Al[wid * 32 + l15][lk];
        f16x8 a1 = *(const f16x8*)&Al[wid * 32 + 16 + l15][lk];
        #pragma unroll
        for (int cf = 0; cf < BN / 16; ++cf) {
            f16x8 b = *(const f16x8*)&Bt[cf * 16 + l15][lk];
            acc[0][cf] = __builtin_amdgcn_mfma_f32_16x16x32_f16(a0, b, acc[0][cf], 0, 0, 0);
            acc[1][cf] = __builtin_amdgcn_mfma_f32_16x16x32_f16(a1, b, acc[1][cf], 0, 0, 0);
        }
        __syncthreads();
    }
    // ---- epilogue: bf16 store + fused att ----
    float asv[BN / 16], adv[BN / 16];
    #pragma unroll
    for (int cf = 0; cf < BN / 16; ++cf) {
        int c = cf * 16 + l15;
        asv[cf] = att_src[c]; adv[cf] = att_dst[c];
    }
    #pragma unroll
    for (int rf = 0; rf < 2; ++rf)
        #pragma unroll
        for (int i = 0; i < 4; ++i) {
            int r = row0 + wid * 32 + rf * 16 + (l >> 4) * 4 + i;
            bool ok = r < M;
            if (ok) {
                #pragma unroll
                for (int cf = 0; cf < BN / 16; ++cf)
                    C[(size_t)r * ldc + cf * 16 + l15] = f2bf(acc[rf][cf][i]);
            }
            #pragma unroll
            for (int h = 0; h < NHEADS; ++h) {
                float ps = 0.f, pd = 0.f;
                #pragma unroll
                for (int k = 0; k < 4; ++k) {       // 4 cf per 64-col head
                    int cf = h * 4 + k;
                    ps += acc[rf][cf][i] * asv[cf];
                    pd += acc[rf][cf][i] * adv[cf];
                }
                #pragma unroll
                for (int m = 1; m < 16; m <<= 1) {
                    ps += __shfl_xor(ps, m);
                    pd += __shfl_xor(pd, m);
                }
                if (ok && l15 == 0) {
                    a_src[(size_t)r * NHEADS + h] = ps;
                    a_dst[(size_t)r * NHEADS + h] = pd;
                }
            }
        }
}

// ---------------------------------------------------------------- fused GRU layer (MFMA + gates [+ FC])
// h = GRUCell(x, h0=0). BN=192 covers r/z/n gates in-lane (frags cf, cf+4, cf+8).
// FUSE_FC: out[r][j] = h[r] . fcW[j] via 16-lane shfl reduction; h never stored.
template<bool FUSE_FC>
__global__ __launch_bounds__(256) void k_gru_mfma(int M,
    const _Float16* __restrict__ A,          // M x 64 (fp16)
    const float* __restrict__ Wih,           // 192 x 64 row-major (Bt orientation)
    const float* __restrict__ bih, const float* __restrict__ bhh,
    _Float16* __restrict__ hout,             // M x 64 (fp16), unused if FUSE_FC
    const float* __restrict__ fcW, const float* __restrict__ fcb,
    float* __restrict__ out)                 // M x 3, only if FUSE_FC
{
    __shared__ _Float16 Al[128][72];   // 144 B stride
    __shared__ _Float16 Bt[192][72];
    const int tid = threadIdx.x, wid = tid >> 6, l = tid & 63;
    const int l15 = l & 15, lk = (l >> 4) * 8;
    const int row0 = blockIdx.x * 128;

    f32x4 acc[2][12];
    #pragma unroll
    for (int rf = 0; rf < 2; ++rf)
        #pragma unroll
        for (int cf = 0; cf < 12; ++cf)
            acc[rf][cf] = (f32x4){0.f, 0.f, 0.f, 0.f};

    #pragma unroll
    for (int u = 0; u < 4; ++u) {
        int i = tid + u * 256;
        int r = i >> 3, kq = (i & 7) * 8;
        int ar = row0 + r; ar = ar < M ? ar : M - 1;
        *(f16x8*)&Al[r][kq] = *(const f16x8*)(A + (size_t)ar * 64 + kq);
    }
    if (tid < 192) {
        #pragma unroll
        for (int kq = 0; kq < 64; kq += 4) {
            float4 v = *(const float4*)(Wih + (size_t)tid * 64 + kq);
            Bt[tid][kq + 0] = (_Float16)v.x; Bt[tid][kq + 1] = (_Float16)v.y;
            Bt[tid][kq + 2] = (_Float16)v.z; Bt[tid][kq + 3] = (_Float16)v.w;
        }
    }
    __syncthreads();
    #pragma unroll
    for (int ks = 0; ks < 2; ++ks) {
        f16x8 a0 = *(const f16x8*)&Al[wid * 32 + l15][ks * 32 + lk];
        f16x8 a1 = *(const f16x8*)&Al[wid * 32 + 16 + l15][ks * 32 + lk];
        #pragma unroll
        for (int cf = 0; cf < 12; ++cf) {
            f16x8 b = *(const f16x8*)&Bt[cf * 16 + l15][ks * 32 + lk];
            acc[0][cf] = __builtin_amdgcn_mfma_f32_16x16x32_f16(a0, b, acc[0][cf], 0, 0, 0);
            acc[1][cf] = __builtin_amdgcn_mfma_f32_16x16x32_f16(a1, b, acc[1][cf], 0, 0, 0);
        }
    }
    float fw[3][4];
    if (FUSE_FC) {
        #pragma unroll
        for (int j = 0; j < 3; ++j)
            #pragma unroll
            for (int cf = 0; cf < 4; ++cf)
                fw[j][cf] = fcW[j * 64 + cf * 16 + l15];
    }
    #pragma unroll
    for (int rf = 0; rf < 2; ++rf)
        #pragma unroll
        for (int i = 0; i < 4; ++i) {
            int r = row0 + wid * 32 + rf * 16 + (l >> 4) * 4 + i;
            bool ok = r < M;
            float p0 = 0.f, p1 = 0.f, p2 = 0.f;
            #pragma unroll
            for (int cf = 0; cf < 4; ++cf) {
                int u = cf * 16 + l15;
                float gr = acc[rf][cf][i]     + bih[u]       + bhh[u];
                float gz = acc[rf][cf + 4][i] + bih[64 + u]  + bhh[64 + u];
                float rr = sigm(gr), zz = sigm(gz);
                float nn = tanhf(acc[rf][cf + 8][i] + bih[128 + u] + rr * bhh[128 + u]);
                float hv = (1.0f - zz) * nn;
                if (!FUSE_FC) {
                    if (ok) hout[(size_t)r * 64 + u] = (_Float16)hv;
                } else {
                    p0 += hv * fw[0][cf]; p1 += hv * fw[1][cf]; p2 += hv * fw[2][cf];
                }
            }
            if (FUSE_FC) {
                #pragma unroll
                for (int m = 1; m < 16; m <<= 1) {
                    p0 += __shfl_xor(p0, m);
                    p1 += __shfl_xor(p1, m);
                    p2 += __shfl_xor(p2, m);
                }
                if (ok && l15 == 0) {
                    out[(size_t)r * 3 + 0] = p0 + fcb[0];
                    out[(size_t)r * 3 + 1] = p1 + fcb[1];
                    out[(size_t)r * 3 + 2] = p2 + fcb[2];
                }
            }
        }
}

// ---------------------------------------------------------------- GAT1 aggregation (bf16 gather, fp16 out)
// Single pass, no max (bounded logits; fminf(e,50) guard). Wave/node, subgroup=head.
// Unrolled x4: four edges' gathers in flight.
__global__ __launch_bounds__(256) void k_aggr1(int n, const int* __restrict__ rowptr,
    const int* __restrict__ col, const unsigned short* __restrict__ h1b,
    const float* __restrict__ a_src, const float* __restrict__ a_dst,
    const float* __restrict__ b1, _Float16* __restrict__ x1h)
{
    int v = (blockIdx.x * blockDim.x + threadIdx.x) >> 6;
    int lane = threadIdx.x & 63;
    if (v >= n) return;
    const int sub = lane >> 4;
    const int l   = lane & 15;
    int beg = rowptr[v], end = rowptr[v + 1];
    float ad = a_dst[(size_t)v * NH + sub];

    float sum = 0.0f;
    float4 acc = make_float4(0.f, 0.f, 0.f, 0.f);
    int i = beg;
    for (; i + 3 < end; i += 4) {
        int s0 = col[i], s1 = col[i + 1], s2 = col[i + 2], s3 = col[i + 3];
        float a0 = a_src[(size_t)s0 * NH + sub];
        float a1 = a_src[(size_t)s1 * NH + sub];
        float a2 = a_src[(size_t)s2 * NH + sub];
        float a3 = a_src[(size_t)s3 * NH + sub];
        uint2 u0 = *reinterpret_cast<const uint2*>(h1b + (size_t)s0 * C1 + sub * HD + l * 4);
        uint2 u1 = *reinterpret_cast<const uint2*>(h1b + (size_t)s1 * C1 + sub * HD + l * 4);
        uint2 u2 = *reinterpret_cast<const uint2*>(h1b + (size_t)s2 * C1 + sub * HD + l * 4);
        uint2 u3 = *reinterpret_cast<const uint2*>(h1b + (size_t)s3 * C1 + sub * HD + l * 4);
        float p0 = __expf(fminf(lrelu(a0 + ad), 50.f));
        float p1 = __expf(fminf(lrelu(a1 + ad), 50.f));
        float p2 = __expf(fminf(lrelu(a2 + ad), 50.f));
        float p3 = __expf(fminf(lrelu(a3 + ad), 50.f));
        sum += (p0 + p1) + (p2 + p3);
        acc.x += p0 * bf2f(u0.x & 0xffffu) + p1 * bf2f(u1.x & 0xffffu)
               + p2 * bf2f(u2.x & 0xffffu) + p3 * bf2f(u3.x & 0xffffu);
        acc.y += p0 * bf2f(u0.x >> 16) + p1 * bf2f(u1.x >> 16)
               + p2 * bf2f(u2.x >> 16) + p3 * bf2f(u3.x >> 16);
        acc.z += p0 * bf2f(u0.y & 0xffffu) + p1 * bf2f(u1.y & 0xffffu)
               + p2 * bf2f(u2.y & 0xffffu) + p3 * bf2f(u3.y & 0xffffu);
        acc.w += p0 * bf2f(u0.y >> 16) + p1 * bf2f(u1.y >> 16)
               + p2 * bf2f(u2.y >> 16) + p3 * bf2f(u3.y >> 16);
    }
    for (; i < end; ++i) {
        int s = col[i];
        float as = a_src[(size_t)s * NH + sub];
        uint2 u = *reinterpret_cast<const uint2*>(h1b + (size_t)s * C1 + sub * HD + l * 4);
        float p = __expf(fminf(lrelu(as + ad), 50.f));
        sum += p;
        acc.x += p * bf2f(u.x & 0xffffu);
        acc.y += p * bf2f(u.x >> 16);
        acc.z += p * bf2f(u.y & 0xffffu);
        acc.w += p * bf2f(u.y >> 16);
    }
    float inv = 1.0f / (sum + 1e-16f);
    float4 bb = *reinterpret_cast<const float4*>(b1 + sub * HD + l * 4);
    float rx = acc.x * inv + bb.x, ry = acc.y * inv + bb.y;
    float rz = acc.z * inv + bb.z, rw = acc.w * inv + bb.w;
    _Float16 o[4];
    o[0] = (_Float16)(rx > 0.f ? rx : 0.f);
    o[1] = (_Float16)(ry > 0.f ? ry : 0.f);
    o[2] = (_Float16)(rz > 0.f ? rz : 0.f);
    o[3] = (_Float16)(rw > 0.f ? rw : 0.f);
    *reinterpret_cast<uint2*>(x1h + (size_t)v * C1 + sub * HD + l * 4) = *reinterpret_cast<uint2*>(o);
}

// ---------------------------------------------------------------- GAT2 aggregation (bf16 gather, fp16 out)
__global__ __launch_bounds__(256) void k_aggr2(int n, const int* __restrict__ rowptr,
    const int* __restrict__ col, const unsigned short* __restrict__ h2b,
    const float* __restrict__ a_src, const float* __restrict__ a_dst,
    const float* __restrict__ b2, _Float16* __restrict__ x2h)
{
    int v = (blockIdx.x * blockDim.x + threadIdx.x) >> 6;
    int lane = threadIdx.x & 63;
    if (v >= n) return;
    const int sub = lane >> 4;
    const int l   = lane & 15;
    int beg = rowptr[v], end = rowptr[v + 1];
    float ad = a_dst[v];

    float sum = 0.0f;
    float4 acc = make_float4(0.f, 0.f, 0.f, 0.f);
    for (int i = beg + sub; i < end; i += 4) {
        int s = col[i];
        float p = __expf(fminf(lrelu(a_src[s] + ad), 50.f));
        sum += p;
        uint2 u = *reinterpret_cast<const uint2*>(h2b + (size_t)s * HD + l * 4);
        acc.x += p * bf2f(u.x & 0xffffu);
        acc.y += p * bf2f(u.x >> 16);
        acc.z += p * bf2f(u.y & 0xffffu);
        acc.w += p * bf2f(u.y >> 16);
    }
    sum += __shfl_xor(sum, 16); sum += __shfl_xor(sum, 32);
    acc.x += __shfl_xor(acc.x, 16); acc.x += __shfl_xor(acc.x, 32);
    acc.y += __shfl_xor(acc.y, 16); acc.y += __shfl_xor(acc.y, 32);
    acc.z += __shfl_xor(acc.z, 16); acc.z += __shfl_xor(acc.z, 32);
    acc.w += __shfl_xor(acc.w, 16); acc.w += __shfl_xor(acc.w, 32);

    if (sub == 0) {
        float inv = 1.0f / (sum + 1e-16f);
        float4 bb = *reinterpret_cast<const float4*>(b2 + l * 4);
        _Float16 o[4];
        o[0] = (_Float16)(acc.x * inv + bb.x);
        o[1] = (_Float16)(acc.y * inv + bb.y);
        o[2] = (_Float16)(acc.z * inv + bb.z);
        o[3] = (_Float16)(acc.w * inv + bb.w);
        *reinterpret_cast<uint2*>(x2h + (size_t)v * HD + l * 4) = *reinterpret_cast<uint2*>(o);
    }
}

// ----------------------------------------------------------------
extern "C" void kernel_launch(void* const* d_in, const int* in_sizes, int n_in,
                              void* d_out, int out_size, void* d_ws, size_t ws_size,
                              hipStream_t stream)
{
    const float* x    = (const float*)d_in[0];
    const int*   eidx = (const int*)d_in[1];
    const float* W1   = (const float*)d_in[2];
    const float* aS1  = (const float*)d_in[3];
    const float* aD1  = (const float*)d_in[4];
    const float* b1   = (const float*)d_in[5];
    const float* W2   = (const float*)d_in[6];
    const float* aS2  = (const float*)d_in[7];
    const float* aD2  = (const float*)d_in[8];
    const float* b2   = (const float*)d_in[9];
    const float* Wih0 = (const float*)d_in[10];
    const float* bih0 = (const float*)d_in[12];
    const float* bhh0 = (const float*)d_in[13];
    const float* Wih1 = (const float*)d_in[14];
    const float* bih1 = (const float*)d_in[16];
    const float* bhh1 = (const float*)d_in[17];
    const float* fcW  = (const float*)d_in[18];
    const float* fcb  = (const float*)d_in[19];
    float* out = (float*)d_out;

    const int N = in_sizes[0] / N_FIN;
    const int E = in_sizes[1] / 2;
    const int* esrc = eidx;
    const int* edst = eidx + E;

    // ---- workspace layout ----
    float* f = (float*)d_ws;
    unsigned short* h1b = (unsigned short*)f;              // N*256 bf16 (slot 0)
    _Float16* hg  = (_Float16*)f;                          // N*64 fp16 (slot 0 reuse; h1b dead by GRU)
    _Float16* x1h = (_Float16*)(f + (size_t)N * C1);       // N*256 fp16
    float* g2s = f + 2 * (size_t)N * C1;                   // slot (N*64 floats)
    unsigned short* g2b = (unsigned short*)g2s;            // N*64 bf16
    float* x2s = g2s + (size_t)N * HD;                     // slot (N*64 floats)
    _Float16* x2h = (_Float16*)x2s;                        // N*64 fp16
    float* as1 = x2s + (size_t)N * HD;                     // N*4
    float* ad1 = as1 + (size_t)N * NH;                     // N*4
    float* as2 = ad1 + (size_t)N * NH;                     // N
    float* ad2 = as2 + (size_t)N;                          // N
    int* ip     = (int*)(ad2 + N);
    int* deg    = ip;                      // N
    int* rowptr = deg + N;                 // N+1
    int* cursor = rowptr + N + 1;          // N
    int* incl   = cursor + N;              // N
    int* bsum   = incl + N;                // <=256
    int* col    = bsum + 256;              // E+N

    const int nbN   = (N + 255) / 256;
    const int nbE   = (E + 255) / 256;
    const int nbEN  = (E + N + 255) / 256;
    const int nbW   = (N + 3) / 4;
    const int NB    = (N + 1023) / 1024;
    const int gM    = (N + 127) / 128;

    // ---- CSR build (deg zeroed by memset; self-loops analytic) ----
    hipMemsetAsync(deg, 0, (size_t)N * sizeof(int), stream);
    k_hist<<<nbE, 256, 0, stream>>>(E, edst, deg);
    k_scan_block<<<NB, 1024, 0, stream>>>(N, deg, incl, bsum);
    k_scan_bsum<<<1, 64, 0, stream>>>(NB, bsum);
    k_rowptr<<<nbN, 256, 0, stream>>>(N, incl, bsum, rowptr, cursor);
    k_fill<<<nbEN, 256, 0, stream>>>(E, N, esrc, edst, cursor, col);

    // ---- GAT layer 1: h1b = bf16(x @ W1) + fused att1 ----
    gemm_mfma<256, 4, false><<<gM, 256, 0, stream>>>(
        N, N_FIN, x, N_FIN, W1, C1, h1b, C1, aS1, aD1, as1, ad1);
    k_aggr1<<<nbW, 256, 0, stream>>>(N, rowptr, col, h1b, as1, ad1, b1, x1h);

    // ---- GAT layer 2: g2b = bf16(x1 @ W2) + fused att2 ----
    gemm_mfma<64, 1, true><<<gM, 256, 0, stream>>>(
        N, C1, x1h, C1, W2, HD, g2b, HD, aS2, aD2, as2, ad2);
    k_aggr2<<<nbW, 256, 0, stream>>>(N, rowptr, col, g2b, as2, ad2, b2, x2h);

    // ---- GRU layers (fused gates; layer 2 fuses final FC) ----
    k_gru_mfma<false><<<gM, 256, 0, stream>>>(N, x2h, Wih0, bih0, bhh0, hg,
                                              nullptr, nullptr, nullptr);
    k_gru_mfma<true><<<gM, 256, 0, stream>>>(N, hg, Wih1, bih1, bhh1, nullptr,
                                             fcW, fcb, out);

    (void)n_in; (void)out_size; (void)ws_size;
}